// Round 6
// baseline (4393.494 us; speedup 1.0000x reference)
//
#include <hip/hip_runtime.h>
#include <hip/hip_bf16.h>
#include <cstdint>

#define B_SZn 4
#define SEQ_L 4096
#define D_MODELn 512
#define D_INNERn 1024
#define N_HEADSn 16
#define HEAD_DIMn 64
#define D_STATEn 64
#define CHUNKn 64
#define BL (B_SZn * SEQ_L)               // 16384
#define XDBL_N (N_HEADSn + 2 * D_STATEn) // 144

typedef __hip_bfloat16 bf16;

__device__ __forceinline__ float silu_f(float v) {
    return v / (1.0f + expf(-v));
}
__device__ __forceinline__ float b2f(unsigned short u) {
    return __uint_as_float((unsigned)u << 16);
}
__device__ __forceinline__ unsigned short f2b(float f) {
    bf16 h = __float2bfloat16(f);
    return *(unsigned short*)&h;
}

// load/store helpers for templated GEMM
__device__ __forceinline__ float ldf(const float* p) { return *p; }
__device__ __forceinline__ float ldf(const bf16* p) { return __bfloat162float(*p); }
__device__ __forceinline__ void stf(float* p, float v) { *p = v; }
__device__ __forceinline__ void stf(bf16* p, float v) { *p = __float2bfloat16(v); }

// ---------------------------------------------------------------------------
// Generic f32-compute tiled GEMM: C[M,N] = A[M,K] @ B[K,N], all row-major.
// 64x64 tile, BK=16, 256 threads, 4x4 microtile.
// ---------------------------------------------------------------------------
template <typename TA, typename TO>
__global__ __launch_bounds__(256) void gemm_t(
    const TA* __restrict__ A, const float* __restrict__ B,
    TO* __restrict__ C, int M, int N, int K) {
    __shared__ float As[16][64];  // transposed: As[k][m]
    __shared__ float Bs[16][64];
    const int tid = threadIdx.x;
    const int block_m = blockIdx.y * 64;
    const int block_n = blockIdx.x * 64;
    const int trow = (tid >> 4) * 4;
    const int tcol = (tid & 15) * 4;
    float acc[4][4] = {};
    for (int k0 = 0; k0 < K; k0 += 16) {
#pragma unroll
        for (int i = 0; i < 4; ++i) {
            int e = tid * 4 + i;
            int r = e >> 4, cc = e & 15;
            int gr = block_m + r, gc = k0 + cc;
            As[cc][r] = (gr < M && gc < K) ? ldf(&A[(size_t)gr * K + gc]) : 0.f;
        }
#pragma unroll
        for (int i = 0; i < 4; ++i) {
            int e = tid * 4 + i;
            int r = e >> 6, cc = e & 63;
            int gr = k0 + r, gc = block_n + cc;
            Bs[r][cc] = (gr < K && gc < N) ? B[(size_t)gr * N + gc] : 0.f;
        }
        __syncthreads();
#pragma unroll
        for (int kk = 0; kk < 16; ++kk) {
            float a[4], b[4];
#pragma unroll
            for (int i = 0; i < 4; ++i) a[i] = As[kk][trow + i];
#pragma unroll
            for (int j = 0; j < 4; ++j) b[j] = Bs[kk][tcol + j];
#pragma unroll
            for (int i = 0; i < 4; ++i)
#pragma unroll
                for (int j = 0; j < 4; ++j) acc[i][j] += a[i] * b[j];
        }
        __syncthreads();
    }
#pragma unroll
    for (int i = 0; i < 4; ++i) {
        int gr = block_m + trow + i;
        if (gr >= M) continue;
#pragma unroll
        for (int j = 0; j < 4; ++j) {
            int gc = block_n + tcol + j;
            if (gc < N) stf(&C[(size_t)gr * N + gc], acc[i][j]);
        }
    }
}

// ---------------------------------------------------------------------------
// Depthwise conv (width 4, SAME: taps l-1..l+2) + bias + silu, both halves.
// ---------------------------------------------------------------------------
__global__ __launch_bounds__(256) void conv_silu_kernel(
    const bf16* __restrict__ xz,
    const float* __restrict__ kx, const float* __restrict__ bx,
    const float* __restrict__ kz, const float* __restrict__ bz,
    bf16* __restrict__ xi, bf16* __restrict__ zo) {
    const int idx = blockIdx.x * 256 + threadIdx.x;  // BL*256 threads
    const int d4 = (idx & 255) * 4;
    const int bl = idx >> 8;
    const int l = bl & (SEQ_L - 1);
    float ax[4], az[4];
#pragma unroll
    for (int j = 0; j < 4; ++j) { ax[j] = bx[d4 + j]; az[j] = bz[d4 + j]; }
#pragma unroll
    for (int k = 0; k < 4; ++k) {
        int ll = l - 1 + k;
        if (ll < 0 || ll >= SEQ_L) continue;
        const unsigned short* row =
            (const unsigned short*)(xz + (size_t)(bl + (ll - l)) * (2 * D_INNERn));
        ushort4 ux = *(const ushort4*)(row + d4);
        ushort4 uz = *(const ushort4*)(row + D_INNERn + d4);
        float4 wx = *(const float4*)(kx + k * D_INNERn + d4);
        float4 wz = *(const float4*)(kz + k * D_INNERn + d4);
        ax[0] += b2f(ux.x) * wx.x; ax[1] += b2f(ux.y) * wx.y;
        ax[2] += b2f(ux.z) * wx.z; ax[3] += b2f(ux.w) * wx.w;
        az[0] += b2f(uz.x) * wz.x; az[1] += b2f(uz.y) * wz.y;
        az[2] += b2f(uz.z) * wz.z; az[3] += b2f(uz.w) * wz.w;
    }
    ushort4 ox, oz;
    ox.x = f2b(silu_f(ax[0])); ox.y = f2b(silu_f(ax[1]));
    ox.z = f2b(silu_f(ax[2])); ox.w = f2b(silu_f(ax[3]));
    oz.x = f2b(silu_f(az[0])); oz.y = f2b(silu_f(az[1]));
    oz.z = f2b(silu_f(az[2])); oz.w = f2b(silu_f(az[3]));
    *(ushort4*)((unsigned short*)xi + (size_t)bl * D_INNERn + d4) = ox;
    *(ushort4*)((unsigned short*)zo + (size_t)bl * D_INNERn + d4) = oz;
}

// ---------------------------------------------------------------------------
// dt = softplus(x_dbl[..., :16] + dt_bias)
// ---------------------------------------------------------------------------
__global__ __launch_bounds__(256) void dt_kernel(
    const float* __restrict__ xdbl, const float* __restrict__ dt_bias,
    float* __restrict__ dtp) {
    const int idx = blockIdx.x * 256 + threadIdx.x;  // BL*16
    const int h = idx & 15;
    const int r = idx >> 4;
    float v = xdbl[(size_t)r * XDBL_N + h] + dt_bias[h];
    dtp[idx] = (v > 20.f) ? v : log1pf(expf(v));
}

// ---------------------------------------------------------------------------
// EXACT sequential SSD recurrence:
//   h_l[p][n] = exp(A*dt_l) * h_{l-1}[p][n] + dt_l * B_l[n] * x_l[p]
//   y_l[p]    = sum_n C_l[n] * h_l[p][n] + D * x_l[p]
// One block per (b,h); thread (p=tid>>2, q=tid&3) owns h[p][q*16..q*16+15].
// ---------------------------------------------------------------------------
__global__ __launch_bounds__(256) void ssd_seq_kernel(
    const float* __restrict__ xdbl, const bf16* __restrict__ xi,
    const float* __restrict__ dtp, const float* __restrict__ A_log,
    const float* __restrict__ Dvec, float* __restrict__ y) {
    const int bh = blockIdx.x;   // 0..63 = b*16 + h
    const int h = bh & 15;
    const int b = bh >> 4;
    const int tid = threadIdx.x;
    const int p = tid >> 2;      // 0..63
    const int q = tid & 3;       // 0..3 -> n range [q*16, q*16+16)
    const float Ah = -expf(A_log[h]);
    const float Dh = Dvec[h];
    __shared__ float sB[64], sC[64], sX[64], sDt[1];
    float hreg[16];
#pragma unroll
    for (int j = 0; j < 16; ++j) hreg[j] = 0.f;

    float pre = 0.f;
    {
        const size_t row = (size_t)b * SEQ_L;  // l = 0
        if (tid < 128) pre = xdbl[row * XDBL_N + N_HEADSn + tid];
        else if (tid < 192)
            pre = __bfloat162float(xi[row * D_INNERn + h * HEAD_DIMn + (tid - 128)]);
        else if (tid == 192) pre = dtp[row * N_HEADSn + h];
    }
    for (int l = 0; l < SEQ_L; ++l) {
        if (tid < 64) sB[tid] = pre;
        else if (tid < 128) sC[tid - 64] = pre;
        else if (tid < 192) sX[tid - 128] = pre;
        else if (tid == 192) sDt[0] = pre;
        __syncthreads();
        if (l + 1 < SEQ_L) {
            const size_t row = (size_t)b * SEQ_L + (l + 1);
            if (tid < 128) pre = xdbl[row * XDBL_N + N_HEADSn + tid];
            else if (tid < 192)
                pre = __bfloat162float(xi[row * D_INNERn + h * HEAD_DIMn + (tid - 128)]);
            else if (tid == 192) pre = dtp[row * N_HEADSn + h];
        }
        const float dtl = sDt[0];
        const float a = expf(Ah * dtl);
        const float xp = sX[p];
        const float coef = dtl * xp;
        float part = 0.f;
#pragma unroll
        for (int j = 0; j < 16; ++j) {
            const int n = q * 16 + j;
            hreg[j] = a * hreg[j] + sB[n] * coef;
            part += sC[n] * hreg[j];
        }
        part += __shfl_xor(part, 1);
        part += __shfl_xor(part, 2);
        if (q == 0)
            y[((size_t)b * SEQ_L + l) * D_INNERn + h * HEAD_DIMn + p] = part + Dh * xp;
        __syncthreads();
    }
}

// ---------------------------------------------------------------------------
// y = RMSNorm(y * silu(z)) * norm_weight   (one block per row, in place, f32)
// ---------------------------------------------------------------------------
__global__ __launch_bounds__(256) void gate_norm_kernel(
    float* __restrict__ y, const bf16* __restrict__ zb,
    const float* __restrict__ nw) {
    const int row = blockIdx.x;
    const int tid = threadIdx.x;
    const size_t base = (size_t)row * D_INNERn + tid * 4;
    float4 yv = *(const float4*)(y + base);
    ushort4 zu = *(const ushort4*)((const unsigned short*)zb + base);
    float v0 = yv.x * silu_f(b2f(zu.x));
    float v1 = yv.y * silu_f(b2f(zu.y));
    float v2 = yv.z * silu_f(b2f(zu.z));
    float v3 = yv.w * silu_f(b2f(zu.w));
    float ss = v0 * v0 + v1 * v1 + v2 * v2 + v3 * v3;
#pragma unroll
    for (int o = 32; o > 0; o >>= 1) ss += __shfl_xor(ss, o);
    __shared__ float sred[4];
    if ((tid & 63) == 0) sred[tid >> 6] = ss;
    __syncthreads();
    float total = sred[0] + sred[1] + sred[2] + sred[3];
    float scale = rsqrtf(total * (1.0f / D_INNERn) + 1e-5f);
    float4 wv = *(const float4*)(nw + tid * 4);
    float4 o4;
    o4.x = v0 * scale * wv.x;
    o4.y = v1 * scale * wv.y;
    o4.z = v2 * scale * wv.z;
    o4.w = v3 * scale * wv.w;
    *(float4*)(y + base) = o4;
}

// ---------------------------------------------------------------------------
extern "C" void kernel_launch(void* const* d_in, const int* in_sizes, int n_in,
                              void* d_out, int out_size, void* d_ws, size_t ws_size,
                              hipStream_t stream) {
    (void)in_sizes; (void)n_in; (void)out_size; (void)ws_size;
    // Inputs are f32 (verified: round-5 runtime dtype probe + npz size math).
    const float* x       = (const float*)d_in[0];
    const float* W_in    = (const float*)d_in[1];
    const float* ckx     = (const float*)d_in[2];
    const float* cbx     = (const float*)d_in[3];
    const float* ckz     = (const float*)d_in[4];
    const float* cbz     = (const float*)d_in[5];
    const float* W_xdbl  = (const float*)d_in[6];
    const float* dt_bias = (const float*)d_in[7];
    const float* A_log   = (const float*)d_in[8];
    const float* Dvec    = (const float*)d_in[9];
    const float* nw      = (const float*)d_in[10];
    const float* W_out   = (const float*)d_in[11];
    // Output dtype = reference output dtype = FLOAT32 (round 1's bf16-output
    // inference was wrong: the traceback showed code context, not the branch).
    float* out = (float*)d_out;
    char* w = (char*)d_ws;

    // Workspace layout (bytes), NO aliasing, total ~202 MiB (proven safe):
    bf16*  xz   = (bf16*)(w);               // [BL][2048] bf16 = 67,108,864
    bf16*  xi   = (bf16*)(w + 67108864);    // [BL][1024] bf16 = 33,554,432
    bf16*  zb   = (bf16*)(w + 100663296);   // [BL][1024] bf16 = 33,554,432
    float* y    = (float*)(w + 134217728);  // [BL][1024] f32  = 67,108,864
    float* xdbl = (float*)(w + 201326592);  // [BL][144] f32   =  9,437,184
    float* dtp  = (float*)(w + 210763776);  // [BL][16] f32    =  1,048,576

    // 1. xz = x @ W_in   (16384 x 2048 x 512), store bf16
    gemm_t<float, bf16><<<dim3(2048 / 64, BL / 64), 256, 0, stream>>>(
        x, W_in, xz, BL, 2048, D_MODELn);
    // 2. conv + silu -> xi, zb (bf16)
    conv_silu_kernel<<<BL, 256, 0, stream>>>(xz, ckx, cbx, ckz, cbz, xi, zb);
    // 3. x_dbl = xi @ W_xdbl  (16384 x 144 x 1024), f32 out
    gemm_t<bf16, float><<<dim3((XDBL_N + 63) / 64, BL / 64), 256, 0, stream>>>(
        xi, W_xdbl, xdbl, BL, XDBL_N, D_INNERn);
    // 4. dt = softplus(...)
    dt_kernel<<<BL * N_HEADSn / 256, 256, 0, stream>>>(xdbl, dt_bias, dtp);
    // 5. EXACT sequential SSD -> y (includes D*x term)
    ssd_seq_kernel<<<B_SZn * N_HEADSn, 256, 0, stream>>>(
        xdbl, xi, dtp, A_log, Dvec, y);
    // 6. gating + RMS norm (y in place, f32)
    gate_norm_kernel<<<BL, 256, 0, stream>>>(y, zb, nw);
    // 7. out = y @ W_out  (16384 x 512 x 1024), store FLOAT32 to d_out
    gemm_t<float, float><<<dim3(512 / 64, BL / 64), 256, 0, stream>>>(
        y, W_out, out, BL, D_MODELn, D_INNERn);
}

// Round 7
// 3138.553 us; speedup vs baseline: 1.3998x; 1.3998x over previous
//
#include <hip/hip_runtime.h>
#include <hip/hip_bf16.h>
#include <cstdint>

#define B_SZn 4
#define SEQ_L 4096
#define D_MODELn 512
#define D_INNERn 1024
#define N_HEADSn 16
#define HEAD_DIMn 64
#define D_STATEn 64
#define CHUNKn 64
#define NCHUNK (SEQ_L / CHUNKn)          // 64
#define BL (B_SZn * SEQ_L)               // 16384
#define XDBL_N (N_HEADSn + 2 * D_STATEn) // 144

typedef __hip_bfloat16 bf16;

__device__ __forceinline__ float silu_f(float v) {
    return v / (1.0f + expf(-v));
}
__device__ __forceinline__ float b2f(unsigned short u) {
    return __uint_as_float((unsigned)u << 16);
}
__device__ __forceinline__ unsigned short f2b(float f) {
    bf16 h = __float2bfloat16(f);
    return *(unsigned short*)&h;
}

// load/store helpers for templated GEMM
__device__ __forceinline__ float ldf(const float* p) { return *p; }
__device__ __forceinline__ float ldf(const bf16* p) { return __bfloat162float(*p); }
__device__ __forceinline__ void stf(float* p, float v) { *p = v; }
__device__ __forceinline__ void stf(bf16* p, float v) { *p = __float2bfloat16(v); }

// ---------------------------------------------------------------------------
// Generic f32-compute tiled GEMM: C[M,N] = A[M,K] @ B[K,N], all row-major.
// 64x64 tile, BK=16, 256 threads, 4x4 microtile.
// ---------------------------------------------------------------------------
template <typename TA, typename TO>
__global__ __launch_bounds__(256) void gemm_t(
    const TA* __restrict__ A, const float* __restrict__ B,
    TO* __restrict__ C, int M, int N, int K) {
    __shared__ float As[16][64];  // transposed: As[k][m]
    __shared__ float Bs[16][64];
    const int tid = threadIdx.x;
    const int block_m = blockIdx.y * 64;
    const int block_n = blockIdx.x * 64;
    const int trow = (tid >> 4) * 4;
    const int tcol = (tid & 15) * 4;
    float acc[4][4] = {};
    for (int k0 = 0; k0 < K; k0 += 16) {
#pragma unroll
        for (int i = 0; i < 4; ++i) {
            int e = tid * 4 + i;
            int r = e >> 4, cc = e & 15;
            int gr = block_m + r, gc = k0 + cc;
            As[cc][r] = (gr < M && gc < K) ? ldf(&A[(size_t)gr * K + gc]) : 0.f;
        }
#pragma unroll
        for (int i = 0; i < 4; ++i) {
            int e = tid * 4 + i;
            int r = e >> 6, cc = e & 63;
            int gr = k0 + r, gc = block_n + cc;
            Bs[r][cc] = (gr < K && gc < N) ? B[(size_t)gr * N + gc] : 0.f;
        }
        __syncthreads();
#pragma unroll
        for (int kk = 0; kk < 16; ++kk) {
            float a[4], b[4];
#pragma unroll
            for (int i = 0; i < 4; ++i) a[i] = As[kk][trow + i];
#pragma unroll
            for (int j = 0; j < 4; ++j) b[j] = Bs[kk][tcol + j];
#pragma unroll
            for (int i = 0; i < 4; ++i)
#pragma unroll
                for (int j = 0; j < 4; ++j) acc[i][j] += a[i] * b[j];
        }
        __syncthreads();
    }
#pragma unroll
    for (int i = 0; i < 4; ++i) {
        int gr = block_m + trow + i;
        if (gr >= M) continue;
#pragma unroll
        for (int j = 0; j < 4; ++j) {
            int gc = block_n + tcol + j;
            if (gc < N) stf(&C[(size_t)gr * N + gc], acc[i][j]);
        }
    }
}

// ---------------------------------------------------------------------------
// Depthwise conv (width 4, SAME: taps l-1..l+2) + bias + silu, both halves.
// ---------------------------------------------------------------------------
__global__ __launch_bounds__(256) void conv_silu_kernel(
    const bf16* __restrict__ xz,
    const float* __restrict__ kx, const float* __restrict__ bx,
    const float* __restrict__ kz, const float* __restrict__ bz,
    bf16* __restrict__ xi, bf16* __restrict__ zo) {
    const int idx = blockIdx.x * 256 + threadIdx.x;  // BL*256 threads
    const int d4 = (idx & 255) * 4;
    const int bl = idx >> 8;
    const int l = bl & (SEQ_L - 1);
    float ax[4], az[4];
#pragma unroll
    for (int j = 0; j < 4; ++j) { ax[j] = bx[d4 + j]; az[j] = bz[d4 + j]; }
#pragma unroll
    for (int k = 0; k < 4; ++k) {
        int ll = l - 1 + k;
        if (ll < 0 || ll >= SEQ_L) continue;
        const unsigned short* row =
            (const unsigned short*)(xz + (size_t)(bl + (ll - l)) * (2 * D_INNERn));
        ushort4 ux = *(const ushort4*)(row + d4);
        ushort4 uz = *(const ushort4*)(row + D_INNERn + d4);
        float4 wx = *(const float4*)(kx + k * D_INNERn + d4);
        float4 wz = *(const float4*)(kz + k * D_INNERn + d4);
        ax[0] += b2f(ux.x) * wx.x; ax[1] += b2f(ux.y) * wx.y;
        ax[2] += b2f(ux.z) * wx.z; ax[3] += b2f(ux.w) * wx.w;
        az[0] += b2f(uz.x) * wz.x; az[1] += b2f(uz.y) * wz.y;
        az[2] += b2f(uz.z) * wz.z; az[3] += b2f(uz.w) * wz.w;
    }
    ushort4 ox, oz;
    ox.x = f2b(silu_f(ax[0])); ox.y = f2b(silu_f(ax[1]));
    ox.z = f2b(silu_f(ax[2])); ox.w = f2b(silu_f(ax[3]));
    oz.x = f2b(silu_f(az[0])); oz.y = f2b(silu_f(az[1]));
    oz.z = f2b(silu_f(az[2])); oz.w = f2b(silu_f(az[3]));
    *(ushort4*)((unsigned short*)xi + (size_t)bl * D_INNERn + d4) = ox;
    *(ushort4*)((unsigned short*)zo + (size_t)bl * D_INNERn + d4) = oz;
}

// ---------------------------------------------------------------------------
// dt = softplus(x_dbl[..., :16] + dt_bias)
// ---------------------------------------------------------------------------
__global__ __launch_bounds__(256) void dt_kernel(
    const float* __restrict__ xdbl, const float* __restrict__ dt_bias,
    float* __restrict__ dtp) {
    const int idx = blockIdx.x * 256 + threadIdx.x;  // BL*16
    const int h = idx & 15;
    const int r = idx >> 4;
    float v = xdbl[(size_t)r * XDBL_N + h] + dt_bias[h];
    dtp[idx] = (v > 20.f) ? v : log1pf(expf(v));
}

// ---------------------------------------------------------------------------
// Per-(b,c,h) SSD chunk: Y_diag (+ D*x) and per-chunk states.
// Equivalence to sequential scan verified (r2 vs r3 bit-identical signature).
// ---------------------------------------------------------------------------
__global__ __launch_bounds__(256) void ssd_chunk_kernel(
    const float* __restrict__ xdbl, const bf16* __restrict__ xi,
    const float* __restrict__ dtp, const float* __restrict__ A_log,
    const float* __restrict__ Dvec,
    float* __restrict__ y, float* __restrict__ S,
    float* __restrict__ acum_g, float* __restrict__ rchunk) {
    __shared__ float sB[64][65];
    __shared__ float sC[64][65];   // reused as G after phase 2
    __shared__ float sX[64][65];
    __shared__ float sdtp[64], sacum[64], sw[64];
    const int bid = blockIdx.x;          // ((b*64 + c)*16 + h)
    const int h = bid & 15;
    const int bc = bid >> 4;
    const int c = bc & (NCHUNK - 1);
    const int b = bc >> 6;
    const int tid = threadIdx.x;
    const int row0 = b * SEQ_L + c * CHUNKn;
    const float Ah = -expf(A_log[h]);

    if (tid < 64) sdtp[tid] = dtp[(size_t)(row0 + tid) * N_HEADSn + h];
    __syncthreads();
    if (tid == 0) {
        float s = 0.f;
#pragma unroll
        for (int i = 0; i < 64; ++i) { s += Ah * sdtp[i]; sacum[i] = s; }
    }
    __syncthreads();
    if (tid < 64) {
        acum_g[(size_t)bid * 64 + tid] = sacum[tid];
        sw[tid] = expf(sacum[63] - sacum[tid]) * sdtp[tid];
    }
    if (tid == 0) rchunk[bid] = expf(sacum[63]);
#pragma unroll
    for (int it = 0; it < 16; ++it) {
        int e = tid + it * 256;
        int s_ = e >> 6, n = e & 63;
        const float* xr = xdbl + (size_t)(row0 + s_) * XDBL_N;
        sB[s_][n] = xr[N_HEADSn + n];
        sC[s_][n] = xr[N_HEADSn + D_STATEn + n];
        sX[s_][n] = __bfloat162float(xi[(size_t)(row0 + s_) * D_INNERn + h * HEAD_DIMn + n]);
    }
    __syncthreads();
    // G[l][s] = sum_n C[l,n]*B[s,n] * mask * exp(acum_l - acum_s) * dt_s
    float greg[16];
#pragma unroll
    for (int it = 0; it < 16; ++it) {
        int e = tid + it * 256;
        int l = e >> 6, s_ = e & 63;
        float g = 0.f;
        for (int n = 0; n < 64; ++n) g += sC[l][n] * sB[s_][n];
        greg[it] = (l >= s_) ? g * expf(sacum[l] - sacum[s_]) * sdtp[s_] : 0.f;
    }
    __syncthreads();
#pragma unroll
    for (int it = 0; it < 16; ++it) {
        int e = tid + it * 256;
        int l = e >> 6, s_ = e & 63;
        sC[l][s_] = greg[it];   // sC now holds G
    }
    __syncthreads();
    const float Dh = Dvec[h];
    // Y_diag[l][p] = sum_s G[l][s]*X[s][p]  (+ D*x)
#pragma unroll
    for (int it = 0; it < 16; ++it) {
        int e = tid + it * 256;
        int l = e >> 6, p = e & 63;
        float acc = Dh * sX[l][p];
        for (int s_ = 0; s_ < 64; ++s_) acc += sC[l][s_] * sX[s_][p];
        y[(size_t)(row0 + l) * D_INNERn + h * HEAD_DIMn + p] = acc;
    }
    // states[p][n] = sum_s B[s,n] * w[s] * X[s,p]
#pragma unroll
    for (int it = 0; it < 16; ++it) {
        int e = tid + it * 256;
        int p = e >> 6, n = e & 63;
        float acc = 0.f;
        for (int s_ = 0; s_ < 64; ++s_) acc += sB[s_][n] * (sw[s_] * sX[s_][p]);
        S[(size_t)bid * 4096 + e] = acc;
    }
}

// ---------------------------------------------------------------------------
// Inter-chunk scan: in-place, S[c] becomes the state ENTERING chunk c.
// ---------------------------------------------------------------------------
__global__ __launch_bounds__(256) void chunk_scan_kernel(
    float* __restrict__ S, const float* __restrict__ rchunk) {
    const int idx = blockIdx.x * 256 + threadIdx.x;  // 4*16*4096 threads
    const int pn = idx & 4095;
    const int bh = idx >> 12;
    const int h = bh & 15;
    const int b = bh >> 4;
    float P = 0.f;
    for (int c = 0; c < NCHUNK; ++c) {
        int bid = (b * NCHUNK + c) * N_HEADSn + h;
        size_t off = (size_t)bid * 4096 + pn;
        float s = S[off];
        S[off] = P;
        P = rchunk[bid] * P + s;
    }
}

// ---------------------------------------------------------------------------
// Y_off[l][p] = exp(acum[l]) * sum_n C[l,n] * P[p,n];  y += Y_off
// ---------------------------------------------------------------------------
__global__ __launch_bounds__(256) void yoff_kernel(
    const float* __restrict__ xdbl, const float* __restrict__ S,
    const float* __restrict__ acum_g, float* __restrict__ y) {
    __shared__ float sC[64][65];
    __shared__ float sP[64][65];
    __shared__ float se[64];
    const int bid = blockIdx.x;
    const int h = bid & 15;
    const int bc = bid >> 4;
    const int c = bc & (NCHUNK - 1);
    const int b = bc >> 6;
    const int tid = threadIdx.x;
    const int row0 = b * SEQ_L + c * CHUNKn;
    if (tid < 64) se[tid] = expf(acum_g[(size_t)bid * 64 + tid]);
#pragma unroll
    for (int it = 0; it < 16; ++it) {
        int e = tid + it * 256;
        int r = e >> 6, n = e & 63;
        sC[r][n] = xdbl[(size_t)(row0 + r) * XDBL_N + N_HEADSn + D_STATEn + n];
        sP[r][n] = S[(size_t)bid * 4096 + e];  // [p][n]
    }
    __syncthreads();
#pragma unroll
    for (int it = 0; it < 16; ++it) {
        int e = tid + it * 256;
        int l = e >> 6, p = e & 63;
        float acc = 0.f;
        for (int n = 0; n < 64; ++n) acc += sC[l][n] * sP[p][n];
        y[(size_t)(row0 + l) * D_INNERn + h * HEAD_DIMn + p] += acc * se[l];
    }
}

// ---------------------------------------------------------------------------
// y = RMSNorm(y * silu(z)) * norm_weight   (one block per row, in place, f32)
// ---------------------------------------------------------------------------
__global__ __launch_bounds__(256) void gate_norm_kernel(
    float* __restrict__ y, const bf16* __restrict__ zb,
    const float* __restrict__ nw) {
    const int row = blockIdx.x;
    const int tid = threadIdx.x;
    const size_t base = (size_t)row * D_INNERn + tid * 4;
    float4 yv = *(const float4*)(y + base);
    ushort4 zu = *(const ushort4*)((const unsigned short*)zb + base);
    float v0 = yv.x * silu_f(b2f(zu.x));
    float v1 = yv.y * silu_f(b2f(zu.y));
    float v2 = yv.z * silu_f(b2f(zu.z));
    float v3 = yv.w * silu_f(b2f(zu.w));
    float ss = v0 * v0 + v1 * v1 + v2 * v2 + v3 * v3;
#pragma unroll
    for (int o = 32; o > 0; o >>= 1) ss += __shfl_xor(ss, o);
    __shared__ float sred[4];
    if ((tid & 63) == 0) sred[tid >> 6] = ss;
    __syncthreads();
    float total = sred[0] + sred[1] + sred[2] + sred[3];
    float scale = rsqrtf(total * (1.0f / D_INNERn) + 1e-5f);
    float4 wv = *(const float4*)(nw + tid * 4);
    float4 o4;
    o4.x = v0 * scale * wv.x;
    o4.y = v1 * scale * wv.y;
    o4.z = v2 * scale * wv.z;
    o4.w = v3 * scale * wv.w;
    *(float4*)(y + base) = o4;
}

// ---------------------------------------------------------------------------
extern "C" void kernel_launch(void* const* d_in, const int* in_sizes, int n_in,
                              void* d_out, int out_size, void* d_ws, size_t ws_size,
                              hipStream_t stream) {
    (void)in_sizes; (void)n_in; (void)out_size; (void)ws_size;
    const float* x       = (const float*)d_in[0];
    const float* W_in    = (const float*)d_in[1];
    const float* ckx     = (const float*)d_in[2];
    const float* cbx     = (const float*)d_in[3];
    const float* ckz     = (const float*)d_in[4];
    const float* cbz     = (const float*)d_in[5];
    const float* W_xdbl  = (const float*)d_in[6];
    const float* dt_bias = (const float*)d_in[7];
    const float* A_log   = (const float*)d_in[8];
    const float* Dvec    = (const float*)d_in[9];
    const float* nw      = (const float*)d_in[10];
    const float* W_out   = (const float*)d_in[11];
    float* out = (float*)d_out;   // f32 output (round-6 verified)
    char* w = (char*)d_ws;

    // Workspace layout (bytes), total 212,877,312 < 256 MiB:
    bf16*  xz     = (bf16*)(w);               // [BL][2048] bf16 = 67,108,864
    float* y      = (float*)(w);              // alias: xz dead after conv (exact fit)
    bf16*  xi     = (bf16*)(w + 67108864);    // [BL][1024] bf16 = 33,554,432
    bf16*  zb     = (bf16*)(w + 100663296);   // [BL][1024] bf16 = 33,554,432
    float* S      = (float*)(w + 134217728);  // [4096][4096] f32 = 67,108,864
    float* xdbl   = (float*)(w + 201326592);  // [BL][144] f32   =  9,437,184
    float* dtp    = (float*)(w + 210763776);  // [BL][16] f32    =  1,048,576
    float* acum   = (float*)(w + 211812352);  // [4096][64] f32  =  1,048,576
    float* rchunk = (float*)(w + 212860928);  // [4096] f32      =     16,384

    // 1. xz = x @ W_in   (16384 x 2048 x 512), store bf16
    gemm_t<float, bf16><<<dim3(2048 / 64, BL / 64), 256, 0, stream>>>(
        x, W_in, xz, BL, 2048, D_MODELn);
    // 2. conv + silu -> xi, zb (bf16)
    conv_silu_kernel<<<BL, 256, 0, stream>>>(xz, ckx, cbx, ckz, cbz, xi, zb);
    // 3. x_dbl = xi @ W_xdbl  (16384 x 144 x 1024), f32 out
    gemm_t<bf16, float><<<dim3((XDBL_N + 63) / 64, BL / 64), 256, 0, stream>>>(
        xi, W_xdbl, xdbl, BL, XDBL_N, D_INNERn);
    // 4. dt = softplus(...)
    dt_kernel<<<BL * N_HEADSn / 256, 256, 0, stream>>>(xdbl, dt_bias, dtp);
    // 5. SSD per-chunk: Y_diag + states (y aliases dead xz region)
    ssd_chunk_kernel<<<B_SZn * NCHUNK * N_HEADSn, 256, 0, stream>>>(
        xdbl, xi, dtp, A_log, Dvec, y, S, acum, rchunk);
    // 6. inter-chunk scan (in place)
    chunk_scan_kernel<<<B_SZn * N_HEADSn * 4096 / 256, 256, 0, stream>>>(S, rchunk);
    // 7. Y_off accumulate
    yoff_kernel<<<B_SZn * NCHUNK * N_HEADSn, 256, 0, stream>>>(xdbl, S, acum, y);
    // 8. gating + RMS norm (y in place, f32)
    gate_norm_kernel<<<BL, 256, 0, stream>>>(y, zb, nw);
    // 9. out = y @ W_out  (16384 x 512 x 1024), store f32 to d_out
    gemm_t<float, float><<<dim3(512 / 64, BL / 64), 256, 0, stream>>>(
        y, W_out, out, BL, D_MODELn, D_INNERn);
}

// Round 8
// 1943.097 us; speedup vs baseline: 2.2611x; 1.6152x over previous
//
#include <hip/hip_runtime.h>
#include <hip/hip_bf16.h>
#include <cstdint>

#define B_SZn 4
#define SEQ_L 4096
#define D_MODELn 512
#define D_INNERn 1024
#define N_HEADSn 16
#define HEAD_DIMn 64
#define D_STATEn 64
#define CHUNKn 64
#define NCHUNK (SEQ_L / CHUNKn)          // 64
#define BL (B_SZn * SEQ_L)               // 16384
#define XDBL_N (N_HEADSn + 2 * D_STATEn) // 144

typedef __hip_bfloat16 bf16;
typedef __bf16 bf16x8 __attribute__((ext_vector_type(8)));
typedef float f32x4 __attribute__((ext_vector_type(4)));

__device__ __forceinline__ float silu_f(float v) {
    return v / (1.0f + expf(-v));
}
__device__ __forceinline__ float b2f(unsigned short u) {
    return __uint_as_float((unsigned)u << 16);
}
__device__ __forceinline__ unsigned short f2b(float f) {
    bf16 h = __float2bfloat16(f);
    return *(unsigned short*)&h;
}
__device__ __forceinline__ void stf(float* p, float v) { *p = v; }
__device__ __forceinline__ void stf(bf16* p, float v) { *p = __float2bfloat16(v); }

// ---------------------------------------------------------------------------
// x (f32) -> bf16 elementwise convert
// ---------------------------------------------------------------------------
__global__ __launch_bounds__(256) void cvt_f32_bf16(
    const float* __restrict__ in, bf16* __restrict__ out) {
    const int idx = blockIdx.x * 256 + threadIdx.x;
    float4 v = *(const float4*)(in + (size_t)idx * 4);
    ushort4 o;
    o.x = f2b(v.x); o.y = f2b(v.y); o.z = f2b(v.z); o.w = f2b(v.w);
    *(ushort4*)((unsigned short*)out + (size_t)idx * 4) = o;
}

// ---------------------------------------------------------------------------
// Transpose + convert: out[c][r] = bf16(in[r][c]).  in [R][C] f32.
// ---------------------------------------------------------------------------
__global__ __launch_bounds__(256) void transpose_cvt(
    const float* __restrict__ in, bf16* __restrict__ out, int R, int C) {
    __shared__ float t[32][33];
    const int bc = blockIdx.x * 32, br = blockIdx.y * 32;
    const int tx = threadIdx.x & 31, ty = threadIdx.x >> 5;  // ty 0..7
#pragma unroll
    for (int i = ty; i < 32; i += 8) {
        int r = br + i, c = bc + tx;
        t[i][tx] = (r < R && c < C) ? in[(size_t)r * C + c] : 0.f;
    }
    __syncthreads();
#pragma unroll
    for (int i = ty; i < 32; i += 8) {
        int c = bc + i, r = br + tx;
        if (c < C && r < R) out[(size_t)c * R + r] = __float2bfloat16(t[tx][i]);
    }
}

// ---------------------------------------------------------------------------
// bf16 MFMA GEMM: C[M,N] = A[M,K] @ Bt[N,K]^T.  A,Bt bf16 row-major
// (both K-contiguous). 128x128 tile, BK=32, 256 thr = 4 waves (2x2),
// wave = 64x64 out = 4x4 fragments of 16x16x32 MFMA.
// M,K multiples of 32; N bounds-checked.
// ---------------------------------------------------------------------------
template <typename TO>
__global__ __launch_bounds__(256) void gemm_mfma(
    const bf16* __restrict__ A, const bf16* __restrict__ Bt,
    TO* __restrict__ C, int M, int N, int K) {
    __shared__ __align__(16) unsigned short Al[128][40];  // stride 40: aligned b128,
    __shared__ __align__(16) unsigned short Blds[128][40]; // even bank spread
    const int tid = threadIdx.x;
    const int wave = tid >> 6, lane = tid & 63;
    const int wm = (wave >> 1) * 64, wn = (wave & 1) * 64;
    const int bm = blockIdx.y * 128, bn = blockIdx.x * 128;
    f32x4 acc[4][4];
#pragma unroll
    for (int m = 0; m < 4; ++m)
#pragma unroll
        for (int n = 0; n < 4; ++n) acc[m][n] = (f32x4)(0.f);

    const int lrow = lane & 15, lk8 = (lane >> 4) * 8;
    for (int k0 = 0; k0 < K; k0 += 32) {
        // stage A tile: 128 rows x 32 k (bf16), 512 x 16B segs, 2 per thread
#pragma unroll
        for (int s = tid; s < 512; s += 256) {
            int r = s >> 2, c8 = (s & 3) * 8;
            int gr = bm + r;
            uint4 v = make_uint4(0, 0, 0, 0);
            if (gr < M) v = *(const uint4*)(A + (size_t)gr * K + k0 + c8);
            *(uint4*)(&Al[r][c8]) = v;
        }
        // stage Bt tile: 128 n-rows x 32 k
#pragma unroll
        for (int s = tid; s < 512; s += 256) {
            int r = s >> 2, c8 = (s & 3) * 8;
            int gr = bn + r;
            uint4 v = make_uint4(0, 0, 0, 0);
            if (gr < N) v = *(const uint4*)(Bt + (size_t)gr * K + k0 + c8);
            *(uint4*)(&Blds[r][c8]) = v;
        }
        __syncthreads();
        bf16x8 af[4], bfr[4];
#pragma unroll
        for (int m = 0; m < 4; ++m)
            af[m] = *(const bf16x8*)(&Al[wm + m * 16 + lrow][lk8]);
#pragma unroll
        for (int n = 0; n < 4; ++n)
            bfr[n] = *(const bf16x8*)(&Blds[wn + n * 16 + lrow][lk8]);
#pragma unroll
        for (int m = 0; m < 4; ++m)
#pragma unroll
            for (int n = 0; n < 4; ++n)
                acc[m][n] = __builtin_amdgcn_mfma_f32_16x16x32_bf16(
                    af[m], bfr[n], acc[m][n], 0, 0, 0);
        __syncthreads();
    }
    // store: D col = lane&15, row = (lane>>4)*4 + r   [m89/m91-verified]
#pragma unroll
    for (int m = 0; m < 4; ++m) {
#pragma unroll
        for (int n = 0; n < 4; ++n) {
#pragma unroll
            for (int r = 0; r < 4; ++r) {
                int row = bm + wm + m * 16 + (lane >> 4) * 4 + r;
                int col = bn + wn + n * 16 + (lane & 15);
                if (row < M && col < N)
                    stf(&C[(size_t)row * N + col], acc[m][n][r]);
            }
        }
    }
}

// ---------------------------------------------------------------------------
// Depthwise conv (width 4, SAME: taps l-1..l+2) + bias + silu, both halves.
// ---------------------------------------------------------------------------
__global__ __launch_bounds__(256) void conv_silu_kernel(
    const bf16* __restrict__ xz,
    const float* __restrict__ kx, const float* __restrict__ bx,
    const float* __restrict__ kz, const float* __restrict__ bz,
    bf16* __restrict__ xi, bf16* __restrict__ zo) {
    const int idx = blockIdx.x * 256 + threadIdx.x;  // BL*256 threads
    const int d4 = (idx & 255) * 4;
    const int bl = idx >> 8;
    const int l = bl & (SEQ_L - 1);
    float ax[4], az[4];
#pragma unroll
    for (int j = 0; j < 4; ++j) { ax[j] = bx[d4 + j]; az[j] = bz[d4 + j]; }
#pragma unroll
    for (int k = 0; k < 4; ++k) {
        int ll = l - 1 + k;
        if (ll < 0 || ll >= SEQ_L) continue;
        const unsigned short* row =
            (const unsigned short*)(xz + (size_t)(bl + (ll - l)) * (2 * D_INNERn));
        ushort4 ux = *(const ushort4*)(row + d4);
        ushort4 uz = *(const ushort4*)(row + D_INNERn + d4);
        float4 wx = *(const float4*)(kx + k * D_INNERn + d4);
        float4 wz = *(const float4*)(kz + k * D_INNERn + d4);
        ax[0] += b2f(ux.x) * wx.x; ax[1] += b2f(ux.y) * wx.y;
        ax[2] += b2f(ux.z) * wx.z; ax[3] += b2f(ux.w) * wx.w;
        az[0] += b2f(uz.x) * wz.x; az[1] += b2f(uz.y) * wz.y;
        az[2] += b2f(uz.z) * wz.z; az[3] += b2f(uz.w) * wz.w;
    }
    ushort4 ox, oz;
    ox.x = f2b(silu_f(ax[0])); ox.y = f2b(silu_f(ax[1]));
    ox.z = f2b(silu_f(ax[2])); ox.w = f2b(silu_f(ax[3]));
    oz.x = f2b(silu_f(az[0])); oz.y = f2b(silu_f(az[1]));
    oz.z = f2b(silu_f(az[2])); oz.w = f2b(silu_f(az[3]));
    *(ushort4*)((unsigned short*)xi + (size_t)bl * D_INNERn + d4) = ox;
    *(ushort4*)((unsigned short*)zo + (size_t)bl * D_INNERn + d4) = oz;
}

// ---------------------------------------------------------------------------
// dt = softplus(x_dbl[..., :16] + dt_bias)
// ---------------------------------------------------------------------------
__global__ __launch_bounds__(256) void dt_kernel(
    const float* __restrict__ xdbl, const float* __restrict__ dt_bias,
    float* __restrict__ dtp) {
    const int idx = blockIdx.x * 256 + threadIdx.x;  // BL*16
    const int h = idx & 15;
    const int r = idx >> 4;
    float v = xdbl[(size_t)r * XDBL_N + h] + dt_bias[h];
    dtp[idx] = (v > 20.f) ? v : log1pf(expf(v));
}

// ---------------------------------------------------------------------------
// Per-(b,c,h) SSD chunk: Y_diag (+ D*x) and per-chunk states.
// ---------------------------------------------------------------------------
__global__ __launch_bounds__(256) void ssd_chunk_kernel(
    const float* __restrict__ xdbl, const bf16* __restrict__ xi,
    const float* __restrict__ dtp, const float* __restrict__ A_log,
    const float* __restrict__ Dvec,
    float* __restrict__ y, float* __restrict__ S,
    float* __restrict__ acum_g, float* __restrict__ rchunk) {
    __shared__ float sB[64][65];
    __shared__ float sC[64][65];   // reused as G after phase 2
    __shared__ float sX[64][65];
    __shared__ float sdtp[64], sacum[64], sw[64];
    const int bid = blockIdx.x;          // ((b*64 + c)*16 + h)
    const int h = bid & 15;
    const int bc = bid >> 4;
    const int c = bc & (NCHUNK - 1);
    const int b = bc >> 6;
    const int tid = threadIdx.x;
    const int row0 = b * SEQ_L + c * CHUNKn;
    const float Ah = -expf(A_log[h]);

    if (tid < 64) sdtp[tid] = dtp[(size_t)(row0 + tid) * N_HEADSn + h];
    __syncthreads();
    if (tid == 0) {
        float s = 0.f;
#pragma unroll
        for (int i = 0; i < 64; ++i) { s += Ah * sdtp[i]; sacum[i] = s; }
    }
    __syncthreads();
    if (tid < 64) {
        acum_g[(size_t)bid * 64 + tid] = sacum[tid];
        sw[tid] = expf(sacum[63] - sacum[tid]) * sdtp[tid];
    }
    if (tid == 0) rchunk[bid] = expf(sacum[63]);
#pragma unroll
    for (int it = 0; it < 16; ++it) {
        int e = tid + it * 256;
        int s_ = e >> 6, n = e & 63;
        const float* xr = xdbl + (size_t)(row0 + s_) * XDBL_N;
        sB[s_][n] = xr[N_HEADSn + n];
        sC[s_][n] = xr[N_HEADSn + D_STATEn + n];
        sX[s_][n] = __bfloat162float(xi[(size_t)(row0 + s_) * D_INNERn + h * HEAD_DIMn + n]);
    }
    __syncthreads();
    float greg[16];
#pragma unroll
    for (int it = 0; it < 16; ++it) {
        int e = tid + it * 256;
        int l = e >> 6, s_ = e & 63;
        float g = 0.f;
        for (int n = 0; n < 64; ++n) g += sC[l][n] * sB[s_][n];
        greg[it] = (l >= s_) ? g * expf(sacum[l] - sacum[s_]) * sdtp[s_] : 0.f;
    }
    __syncthreads();
#pragma unroll
    for (int it = 0; it < 16; ++it) {
        int e = tid + it * 256;
        int l = e >> 6, s_ = e & 63;
        sC[l][s_] = greg[it];   // sC now holds G
    }
    __syncthreads();
    const float Dh = Dvec[h];
#pragma unroll
    for (int it = 0; it < 16; ++it) {
        int e = tid + it * 256;
        int l = e >> 6, p = e & 63;
        float acc = Dh * sX[l][p];
        for (int s_ = 0; s_ < 64; ++s_) acc += sC[l][s_] * sX[s_][p];
        y[(size_t)(row0 + l) * D_INNERn + h * HEAD_DIMn + p] = acc;
    }
#pragma unroll
    for (int it = 0; it < 16; ++it) {
        int e = tid + it * 256;
        int p = e >> 6, n = e & 63;
        float acc = 0.f;
        for (int s_ = 0; s_ < 64; ++s_) acc += sB[s_][n] * (sw[s_] * sX[s_][p]);
        S[(size_t)bid * 4096 + e] = acc;
    }
}

// ---------------------------------------------------------------------------
// Inter-chunk scan: in-place, S[c] becomes the state ENTERING chunk c.
// ---------------------------------------------------------------------------
__global__ __launch_bounds__(256) void chunk_scan_kernel(
    float* __restrict__ S, const float* __restrict__ rchunk) {
    const int idx = blockIdx.x * 256 + threadIdx.x;  // 4*16*4096 threads
    const int pn = idx & 4095;
    const int bh = idx >> 12;
    const int h = bh & 15;
    const int b = bh >> 4;
    float P = 0.f;
    for (int c = 0; c < NCHUNK; ++c) {
        int bid = (b * NCHUNK + c) * N_HEADSn + h;
        size_t off = (size_t)bid * 4096 + pn;
        float s = S[off];
        S[off] = P;
        P = rchunk[bid] * P + s;
    }
}

// ---------------------------------------------------------------------------
// Y_off[l][p] = exp(acum[l]) * sum_n C[l,n] * P[p,n];  y += Y_off
// ---------------------------------------------------------------------------
__global__ __launch_bounds__(256) void yoff_kernel(
    const float* __restrict__ xdbl, const float* __restrict__ S,
    const float* __restrict__ acum_g, float* __restrict__ y) {
    __shared__ float sC[64][65];
    __shared__ float sP[64][65];
    __shared__ float se[64];
    const int bid = blockIdx.x;
    const int h = bid & 15;
    const int bc = bid >> 4;
    const int c = bc & (NCHUNK - 1);
    const int b = bc >> 6;
    const int tid = threadIdx.x;
    const int row0 = b * SEQ_L + c * CHUNKn;
    if (tid < 64) se[tid] = expf(acum_g[(size_t)bid * 64 + tid]);
#pragma unroll
    for (int it = 0; it < 16; ++it) {
        int e = tid + it * 256;
        int r = e >> 6, n = e & 63;
        sC[r][n] = xdbl[(size_t)(row0 + r) * XDBL_N + N_HEADSn + D_STATEn + n];
        sP[r][n] = S[(size_t)bid * 4096 + e];  // [p][n]
    }
    __syncthreads();
#pragma unroll
    for (int it = 0; it < 16; ++it) {
        int e = tid + it * 256;
        int l = e >> 6, p = e & 63;
        float acc = 0.f;
        for (int n = 0; n < 64; ++n) acc += sC[l][n] * sP[p][n];
        y[(size_t)(row0 + l) * D_INNERn + h * HEAD_DIMn + p] += acc * se[l];
    }
}

// ---------------------------------------------------------------------------
// y_bf = bf16( RMSNorm(y * silu(z)) * norm_weight )
// ---------------------------------------------------------------------------
__global__ __launch_bounds__(256) void gate_norm_kernel(
    const float* __restrict__ y, const bf16* __restrict__ zb,
    const float* __restrict__ nw, bf16* __restrict__ y_bf) {
    const int row = blockIdx.x;
    const int tid = threadIdx.x;
    const size_t base = (size_t)row * D_INNERn + tid * 4;
    float4 yv = *(const float4*)(y + base);
    ushort4 zu = *(const ushort4*)((const unsigned short*)zb + base);
    float v0 = yv.x * silu_f(b2f(zu.x));
    float v1 = yv.y * silu_f(b2f(zu.y));
    float v2 = yv.z * silu_f(b2f(zu.z));
    float v3 = yv.w * silu_f(b2f(zu.w));
    float ss = v0 * v0 + v1 * v1 + v2 * v2 + v3 * v3;
#pragma unroll
    for (int o = 32; o > 0; o >>= 1) ss += __shfl_xor(ss, o);
    __shared__ float sred[4];
    if ((tid & 63) == 0) sred[tid >> 6] = ss;
    __syncthreads();
    float total = sred[0] + sred[1] + sred[2] + sred[3];
    float scale = rsqrtf(total * (1.0f / D_INNERn) + 1e-5f);
    float4 wv = *(const float4*)(nw + tid * 4);
    ushort4 o4;
    o4.x = f2b(v0 * scale * wv.x);
    o4.y = f2b(v1 * scale * wv.y);
    o4.z = f2b(v2 * scale * wv.z);
    o4.w = f2b(v3 * scale * wv.w);
    *(ushort4*)((unsigned short*)y_bf + base) = o4;
}

// ---------------------------------------------------------------------------
extern "C" void kernel_launch(void* const* d_in, const int* in_sizes, int n_in,
                              void* d_out, int out_size, void* d_ws, size_t ws_size,
                              hipStream_t stream) {
    (void)in_sizes; (void)n_in; (void)out_size; (void)ws_size;
    const float* x       = (const float*)d_in[0];
    const float* W_in    = (const float*)d_in[1];
    const float* ckx     = (const float*)d_in[2];
    const float* cbx     = (const float*)d_in[3];
    const float* ckz     = (const float*)d_in[4];
    const float* cbz     = (const float*)d_in[5];
    const float* W_xdbl  = (const float*)d_in[6];
    const float* dt_bias = (const float*)d_in[7];
    const float* A_log   = (const float*)d_in[8];
    const float* Dvec    = (const float*)d_in[9];
    const float* nw      = (const float*)d_in[10];
    const float* W_out   = (const float*)d_in[11];
    float* out = (float*)d_out;   // f32 output (round-6 verified)
    char* w = (char*)d_ws;

    // Workspace layout (bytes), total 212,877,312 — EXACTLY the proven size.
    bf16*  xz     = (bf16*)(w);               // [BL][2048] bf16 = 67,108,864
    float* y      = (float*)(w);              // alias: xz dead after conv
    bf16*  xi     = (bf16*)(w + 67108864);    // [BL][1024] bf16 = 33,554,432
    bf16*  zb     = (bf16*)(w + 100663296);   // [BL][1024] bf16 = 33,554,432
    char*  Sreg   = w + 134217728;            // 67,108,864 region, multi-use:
    float* S      = (float*)Sreg;             //   [4096][4096] f32 (SSD phase)
    bf16*  x_bf   = (bf16*)Sreg;              //   prologue: [BL][512] bf16 = 16.8M
    bf16*  W_in_T = (bf16*)(Sreg + 16777216); //   prologue: [2048][512] bf16 = 2.1M
    bf16*  W_xd_T = (bf16*)(Sreg + 18874368); //   prologue: [144][1024] bf16 = 0.3M
    bf16*  y_bf   = (bf16*)Sreg;              //   epilogue: [BL][1024] bf16 = 33.5M
    bf16*  W_o_T  = (bf16*)(Sreg + 33554432); //   epilogue: [512][1024] bf16 = 1.0M
    float* xdbl   = (float*)(w + 201326592);  // [BL][144] f32   =  9,437,184
    float* dtp    = (float*)(w + 210763776);  // [BL][16] f32    =  1,048,576
    float* acum   = (float*)(w + 211812352);  // [4096][64] f32  =  1,048,576
    float* rchunk = (float*)(w + 212860928);  // [4096] f32      =     16,384

    // 0. prologue converts (into S region — dead until ssd_chunk)
    cvt_f32_bf16<<<BL * D_MODELn / 1024, 256, 0, stream>>>(x, x_bf);
    transpose_cvt<<<dim3(2048 / 32, 512 / 32), 256, 0, stream>>>(W_in, W_in_T, 512, 2048);
    transpose_cvt<<<dim3(5, 1024 / 32), 256, 0, stream>>>(W_xdbl, W_xd_T, 1024, 144);
    // 1. xz = x @ W_in  (MFMA, 16384 x 2048 x 512), store bf16
    gemm_mfma<bf16><<<dim3(2048 / 128, BL / 128), 256, 0, stream>>>(
        x_bf, W_in_T, xz, BL, 2048, D_MODELn);
    // 2. conv + silu -> xi, zb (bf16)
    conv_silu_kernel<<<BL, 256, 0, stream>>>(xz, ckx, cbx, ckz, cbz, xi, zb);
    // 3. x_dbl = xi @ W_xdbl  (MFMA, 16384 x 144 x 1024), f32 out
    gemm_mfma<float><<<dim3(2, BL / 128), 256, 0, stream>>>(
        xi, W_xd_T, xdbl, BL, XDBL_N, D_INNERn);
    // 4. dt = softplus(...)
    dt_kernel<<<BL * N_HEADSn / 256, 256, 0, stream>>>(xdbl, dt_bias, dtp);
    // 5. SSD per-chunk: Y_diag + states (y aliases dead xz; S overwrites prologue)
    ssd_chunk_kernel<<<B_SZn * NCHUNK * N_HEADSn, 256, 0, stream>>>(
        xdbl, xi, dtp, A_log, Dvec, y, S, acum, rchunk);
    // 6. inter-chunk scan (in place)
    chunk_scan_kernel<<<B_SZn * N_HEADSn * 4096 / 256, 256, 0, stream>>>(S, rchunk);
    // 7. Y_off accumulate
    yoff_kernel<<<B_SZn * NCHUNK * N_HEADSn, 256, 0, stream>>>(xdbl, S, acum, y);
    // 8. epilogue: W_out^T (S dead after yoff), gate+norm -> y_bf
    transpose_cvt<<<dim3(512 / 32, 1024 / 32), 256, 0, stream>>>(W_out, W_o_T, 1024, 512);
    gate_norm_kernel<<<BL, 256, 0, stream>>>(y, zb, nw, y_bf);
    // 9. out = y @ W_out  (MFMA, 16384 x 512 x 1024), store f32 to d_out
    gemm_mfma<float><<<dim3(512 / 128, BL / 128), 256, 0, stream>>>(
        y_bf, W_o_T, out, BL, D_MODELn, D_INNERn);
}

// Round 9
// 384.991 us; speedup vs baseline: 11.4119x; 5.0471x over previous
//
#include <hip/hip_runtime.h>
#include <hip/hip_bf16.h>
#include <cstdint>

#define B_SZn 4
#define SEQ_L 4096
#define D_MODELn 512
#define D_INNERn 1024
#define N_HEADSn 16
#define HEAD_DIMn 64
#define D_STATEn 64
#define CHUNKn 64
#define NCHUNK (SEQ_L / CHUNKn)          // 64
#define BL (B_SZn * SEQ_L)               // 16384
#define XDBL_N (N_HEADSn + 2 * D_STATEn) // 144

typedef __hip_bfloat16 bf16;
typedef __bf16 bf16x8 __attribute__((ext_vector_type(8)));
typedef float f32x4 __attribute__((ext_vector_type(4)));

__device__ __forceinline__ float silu_f(float v) {
    return v / (1.0f + expf(-v));
}
__device__ __forceinline__ float b2f(unsigned short u) {
    return __uint_as_float((unsigned)u << 16);
}
__device__ __forceinline__ unsigned short f2b(float f) {
    bf16 h = __float2bfloat16(f);
    return *(unsigned short*)&h;
}
__device__ __forceinline__ void stf(float* p, float v) { *p = v; }
__device__ __forceinline__ void stf(bf16* p, float v) { *p = __float2bfloat16(v); }

// ---------------------------------------------------------------------------
// x (f32) -> bf16 elementwise convert
// ---------------------------------------------------------------------------
__global__ __launch_bounds__(256) void cvt_f32_bf16(
    const float* __restrict__ in, bf16* __restrict__ out) {
    const int idx = blockIdx.x * 256 + threadIdx.x;
    float4 v = *(const float4*)(in + (size_t)idx * 4);
    ushort4 o;
    o.x = f2b(v.x); o.y = f2b(v.y); o.z = f2b(v.z); o.w = f2b(v.w);
    *(ushort4*)((unsigned short*)out + (size_t)idx * 4) = o;
}

// ---------------------------------------------------------------------------
// Transpose + convert: out[c][r] = bf16(in[r][c]).  in [R][C] f32.
// ---------------------------------------------------------------------------
__global__ __launch_bounds__(256) void transpose_cvt(
    const float* __restrict__ in, bf16* __restrict__ out, int R, int C) {
    __shared__ float t[32][33];
    const int bc = blockIdx.x * 32, br = blockIdx.y * 32;
    const int tx = threadIdx.x & 31, ty = threadIdx.x >> 5;  // ty 0..7
#pragma unroll
    for (int i = ty; i < 32; i += 8) {
        int r = br + i, c = bc + tx;
        t[i][tx] = (r < R && c < C) ? in[(size_t)r * C + c] : 0.f;
    }
    __syncthreads();
#pragma unroll
    for (int i = ty; i < 32; i += 8) {
        int c = bc + i, r = br + tx;
        if (c < C && r < R) out[(size_t)c * R + r] = __float2bfloat16(t[tx][i]);
    }
}

// ---------------------------------------------------------------------------
// bf16 MFMA GEMM: C[M,N] = A[M,K] @ Bt[N,K]^T.  128x128 tile, BK=32, 4 waves.
// ---------------------------------------------------------------------------
template <typename TO>
__global__ __launch_bounds__(256) void gemm_mfma(
    const bf16* __restrict__ A, const bf16* __restrict__ Bt,
    TO* __restrict__ C, int M, int N, int K) {
    __shared__ __align__(16) unsigned short Al[128][40];
    __shared__ __align__(16) unsigned short Blds[128][40];
    const int tid = threadIdx.x;
    const int wave = tid >> 6, lane = tid & 63;
    const int wm = (wave >> 1) * 64, wn = (wave & 1) * 64;
    const int bm = blockIdx.y * 128, bn = blockIdx.x * 128;
    f32x4 acc[4][4];
#pragma unroll
    for (int m = 0; m < 4; ++m)
#pragma unroll
        for (int n = 0; n < 4; ++n) acc[m][n] = (f32x4)(0.f);

    const int lrow = lane & 15, lk8 = (lane >> 4) * 8;
    for (int k0 = 0; k0 < K; k0 += 32) {
#pragma unroll
        for (int s = tid; s < 512; s += 256) {
            int r = s >> 2, c8 = (s & 3) * 8;
            int gr = bm + r;
            uint4 v = make_uint4(0, 0, 0, 0);
            if (gr < M) v = *(const uint4*)(A + (size_t)gr * K + k0 + c8);
            *(uint4*)(&Al[r][c8]) = v;
        }
#pragma unroll
        for (int s = tid; s < 512; s += 256) {
            int r = s >> 2, c8 = (s & 3) * 8;
            int gr = bn + r;
            uint4 v = make_uint4(0, 0, 0, 0);
            if (gr < N) v = *(const uint4*)(Bt + (size_t)gr * K + k0 + c8);
            *(uint4*)(&Blds[r][c8]) = v;
        }
        __syncthreads();
        bf16x8 af[4], bfr[4];
#pragma unroll
        for (int m = 0; m < 4; ++m)
            af[m] = *(const bf16x8*)(&Al[wm + m * 16 + lrow][lk8]);
#pragma unroll
        for (int n = 0; n < 4; ++n)
            bfr[n] = *(const bf16x8*)(&Blds[wn + n * 16 + lrow][lk8]);
#pragma unroll
        for (int m = 0; m < 4; ++m)
#pragma unroll
            for (int n = 0; n < 4; ++n)
                acc[m][n] = __builtin_amdgcn_mfma_f32_16x16x32_bf16(
                    af[m], bfr[n], acc[m][n], 0, 0, 0);
        __syncthreads();
    }
#pragma unroll
    for (int m = 0; m < 4; ++m) {
#pragma unroll
        for (int n = 0; n < 4; ++n) {
#pragma unroll
            for (int r = 0; r < 4; ++r) {
                int row = bm + wm + m * 16 + (lane >> 4) * 4 + r;
                int col = bn + wn + n * 16 + (lane & 15);
                if (row < M && col < N)
                    stf(&C[(size_t)row * N + col], acc[m][n][r]);
            }
        }
    }
}

// ---------------------------------------------------------------------------
// Depthwise conv (width 4, SAME: taps l-1..l+2) + bias + silu, both halves.
// ---------------------------------------------------------------------------
__global__ __launch_bounds__(256) void conv_silu_kernel(
    const bf16* __restrict__ xz,
    const float* __restrict__ kx, const float* __restrict__ bx,
    const float* __restrict__ kz, const float* __restrict__ bz,
    bf16* __restrict__ xi, bf16* __restrict__ zo) {
    const int idx = blockIdx.x * 256 + threadIdx.x;  // BL*256 threads
    const int d4 = (idx & 255) * 4;
    const int bl = idx >> 8;
    const int l = bl & (SEQ_L - 1);
    float ax[4], az[4];
#pragma unroll
    for (int j = 0; j < 4; ++j) { ax[j] = bx[d4 + j]; az[j] = bz[d4 + j]; }
#pragma unroll
    for (int k = 0; k < 4; ++k) {
        int ll = l - 1 + k;
        if (ll < 0 || ll >= SEQ_L) continue;
        const unsigned short* row =
            (const unsigned short*)(xz + (size_t)(bl + (ll - l)) * (2 * D_INNERn));
        ushort4 ux = *(const ushort4*)(row + d4);
        ushort4 uz = *(const ushort4*)(row + D_INNERn + d4);
        float4 wx = *(const float4*)(kx + k * D_INNERn + d4);
        float4 wz = *(const float4*)(kz + k * D_INNERn + d4);
        ax[0] += b2f(ux.x) * wx.x; ax[1] += b2f(ux.y) * wx.y;
        ax[2] += b2f(ux.z) * wx.z; ax[3] += b2f(ux.w) * wx.w;
        az[0] += b2f(uz.x) * wz.x; az[1] += b2f(uz.y) * wz.y;
        az[2] += b2f(uz.z) * wz.z; az[3] += b2f(uz.w) * wz.w;
    }
    ushort4 ox, oz;
    ox.x = f2b(silu_f(ax[0])); ox.y = f2b(silu_f(ax[1]));
    ox.z = f2b(silu_f(ax[2])); ox.w = f2b(silu_f(ax[3]));
    oz.x = f2b(silu_f(az[0])); oz.y = f2b(silu_f(az[1]));
    oz.z = f2b(silu_f(az[2])); oz.w = f2b(silu_f(az[3]));
    *(ushort4*)((unsigned short*)xi + (size_t)bl * D_INNERn + d4) = ox;
    *(ushort4*)((unsigned short*)zo + (size_t)bl * D_INNERn + d4) = oz;
}

// ---------------------------------------------------------------------------
// dt = softplus(x_dbl[..., :16] + dt_bias)
// ---------------------------------------------------------------------------
__global__ __launch_bounds__(256) void dt_kernel(
    const float* __restrict__ xdbl, const float* __restrict__ dt_bias,
    float* __restrict__ dtp) {
    const int idx = blockIdx.x * 256 + threadIdx.x;  // BL*16
    const int h = idx & 15;
    const int r = idx >> 4;
    float v = xdbl[(size_t)r * XDBL_N + h] + dt_bias[h];
    dtp[idx] = (v > 20.f) ? v : log1pf(expf(v));
}

// ---------------------------------------------------------------------------
// MFMA SSD chunk: per (b,c,h) block, 4 waves.
//   MFMA1: Graw = C·B^T;  mask/scale -> sGb (bf16)
//   MFMA2: Y = G·X (+ D·x) -> y
//   MFMA3: S = X^T·(w·B) -> S
// LDS tiles stride 72 bf16 (144B rows: 16B-aligned b128 fragment reads).
// ---------------------------------------------------------------------------
__global__ __launch_bounds__(256) void ssd_chunk_mfma(
    const float* __restrict__ xdbl, const bf16* __restrict__ xi,
    const float* __restrict__ dtp, const float* __restrict__ A_log,
    const float* __restrict__ Dvec,
    float* __restrict__ y, float* __restrict__ S,
    float* __restrict__ acum_g, float* __restrict__ rchunk) {
    __shared__ __align__(16) unsigned short sBb[64 * 72];  // B[s][n]
    __shared__ __align__(16) unsigned short sCb[64 * 72];  // C[l][n]
    __shared__ __align__(16) unsigned short sXT[64 * 72];  // X^T[p][s]
    __shared__ __align__(16) unsigned short sGb[64 * 72];  // G[l][s]
    __shared__ __align__(16) unsigned short sWB[64 * 72];  // (w·B)^T[n][s]
    __shared__ float sdtp[64], sacum[64], sw[64];
    const int bid = blockIdx.x;          // ((b*64 + c)*16 + h)
    const int h = bid & 15;
    const int bc = bid >> 4;
    const int c = bc & (NCHUNK - 1);
    const int b = bc >> 6;
    const int tid = threadIdx.x;
    const int wave = tid >> 6, lane = tid & 63;
    const int lrow = lane & 15, lk8 = (lane >> 4) * 8;
    const int row0 = b * SEQ_L + c * CHUNKn;
    const float Ah = -expf(A_log[h]);
    const float Dh = Dvec[h];

    if (tid < 64) sdtp[tid] = dtp[(size_t)(row0 + tid) * N_HEADSn + h];
    const unsigned short* xius = (const unsigned short*)xi;
#pragma unroll
    for (int it = 0; it < 16; ++it) {
        int e = tid + it * 256;
        int s = e >> 6, n = e & 63;
        const float* xr = xdbl + (size_t)(row0 + s) * XDBL_N + N_HEADSn;
        sBb[s * 72 + n] = f2b(xr[n]);
        sCb[s * 72 + n] = f2b(xr[D_STATEn + n]);
        sXT[n * 72 + s] = xius[(size_t)(row0 + s) * D_INNERn + h * HEAD_DIMn + n];
    }
    __syncthreads();
    // wave0: 64-lane inclusive scan of Ah*dt (hides under other waves' MFMA1)
    if (wave == 0) {
        float v = Ah * sdtp[lane];
#pragma unroll
        for (int o = 1; o < 64; o <<= 1) {
            float t = __shfl_up(v, o);
            if (lane >= o) v += t;
        }
        sacum[lane] = v;
        float last = __shfl(v, 63);
        sw[lane] = expf(last - v) * sdtp[lane];
        acum_g[(size_t)bid * 64 + lane] = v;
        if (lane == 63) rchunk[bid] = expf(v);
    }
    // MFMA1: rows l = wave*16+lrow, 4 s-tiles, K=n=64
    f32x4 acc1[4];
#pragma unroll
    for (int t = 0; t < 4; ++t) acc1[t] = (f32x4)(0.f);
#pragma unroll
    for (int ks = 0; ks < 2; ++ks) {
        bf16x8 a = *(const bf16x8*)(&sCb[(wave * 16 + lrow) * 72 + ks * 32 + lk8]);
#pragma unroll
        for (int t = 0; t < 4; ++t) {
            bf16x8 bb = *(const bf16x8*)(&sBb[(t * 16 + lrow) * 72 + ks * 32 + lk8]);
            acc1[t] = __builtin_amdgcn_mfma_f32_16x16x32_bf16(a, bb, acc1[t], 0, 0, 0);
        }
    }
    __syncthreads();   // sacum/sw ready; acc1 live in regs
    // mask + decay-scale -> sGb
#pragma unroll
    for (int t = 0; t < 4; ++t) {
#pragma unroll
        for (int r = 0; r < 4; ++r) {
            int l = wave * 16 + (lane >> 4) * 4 + r;
            int s = t * 16 + lrow;
            float val = 0.f;
            if (l >= s) val = acc1[t][r] * expf(sacum[l] - sacum[s]) * sdtp[s];
            sGb[l * 72 + s] = f2b(val);
        }
    }
    // build (w·B)^T
#pragma unroll
    for (int it = 0; it < 16; ++it) {
        int e = tid + it * 256;
        int s = e >> 6, n = e & 63;
        sWB[n * 72 + s] = f2b(sw[s] * b2f(sBb[s * 72 + n]));
    }
    __syncthreads();
    // MFMA2: Y rows l; B = X^T (col=p).  MFMA3: S rows p; B = (wB)^T (col=n).
    f32x4 acc2[4], acc3[4];
#pragma unroll
    for (int t = 0; t < 4; ++t) { acc2[t] = (f32x4)(0.f); acc3[t] = (f32x4)(0.f); }
#pragma unroll
    for (int ks = 0; ks < 2; ++ks) {
        bf16x8 a2 = *(const bf16x8*)(&sGb[(wave * 16 + lrow) * 72 + ks * 32 + lk8]);
        bf16x8 a3 = *(const bf16x8*)(&sXT[(wave * 16 + lrow) * 72 + ks * 32 + lk8]);
#pragma unroll
        for (int t = 0; t < 4; ++t) {
            bf16x8 b2v = *(const bf16x8*)(&sXT[(t * 16 + lrow) * 72 + ks * 32 + lk8]);
            bf16x8 b3v = *(const bf16x8*)(&sWB[(t * 16 + lrow) * 72 + ks * 32 + lk8]);
            acc2[t] = __builtin_amdgcn_mfma_f32_16x16x32_bf16(a2, b2v, acc2[t], 0, 0, 0);
            acc3[t] = __builtin_amdgcn_mfma_f32_16x16x32_bf16(a3, b3v, acc3[t], 0, 0, 0);
        }
    }
#pragma unroll
    for (int t = 0; t < 4; ++t) {
#pragma unroll
        for (int r = 0; r < 4; ++r) {
            int rr = wave * 16 + (lane >> 4) * 4 + r;  // l for Y, p for S
            int cc = t * 16 + lrow;                    // p for Y, n for S
            float xv = b2f(sXT[cc * 72 + rr]);         // X[rr][cc]
            y[(size_t)(row0 + rr) * D_INNERn + h * HEAD_DIMn + cc] = acc2[t][r] + Dh * xv;
            S[(size_t)bid * 4096 + rr * 64 + cc] = acc3[t][r];
        }
    }
}

// ---------------------------------------------------------------------------
// Inter-chunk scan: in-place, S[c] becomes the state ENTERING chunk c.
// ---------------------------------------------------------------------------
__global__ __launch_bounds__(256) void chunk_scan_kernel(
    float* __restrict__ S, const float* __restrict__ rchunk) {
    const int idx = blockIdx.x * 256 + threadIdx.x;  // 4*16*4096 threads
    const int pn = idx & 4095;
    const int bh = idx >> 12;
    const int h = bh & 15;
    const int b = bh >> 4;
    float P = 0.f;
    for (int c = 0; c < NCHUNK; ++c) {
        int bid = (b * NCHUNK + c) * N_HEADSn + h;
        size_t off = (size_t)bid * 4096 + pn;
        float s = S[off];
        S[off] = P;
        P = rchunk[bid] * P + s;
    }
}

// ---------------------------------------------------------------------------
// MFMA Y_off: y[l][p] += exp(acum[l]) * sum_n C[l][n] * P[p][n]
// S (=[p][n]) is already in B-fragment layout — no transpose needed.
// ---------------------------------------------------------------------------
__global__ __launch_bounds__(256) void yoff_mfma(
    const float* __restrict__ xdbl, const float* __restrict__ S,
    const float* __restrict__ acum_g, float* __restrict__ y) {
    __shared__ __align__(16) unsigned short sCb[64 * 72];
    __shared__ __align__(16) unsigned short sP[64 * 72];
    __shared__ float se[64];
    const int bid = blockIdx.x;
    const int h = bid & 15;
    const int bc = bid >> 4;
    const int c = bc & (NCHUNK - 1);
    const int b = bc >> 6;
    const int tid = threadIdx.x;
    const int wave = tid >> 6, lane = tid & 63;
    const int lrow = lane & 15, lk8 = (lane >> 4) * 8;
    const int row0 = b * SEQ_L + c * CHUNKn;
    if (tid < 64) se[tid] = expf(acum_g[(size_t)bid * 64 + tid]);
#pragma unroll
    for (int it = 0; it < 16; ++it) {
        int e = tid + it * 256;
        int r = e >> 6, n = e & 63;
        sCb[r * 72 + n] = f2b(xdbl[(size_t)(row0 + r) * XDBL_N + N_HEADSn + D_STATEn + n]);
        sP[r * 72 + n] = f2b(S[(size_t)bid * 4096 + e]);
    }
    __syncthreads();
    f32x4 acc[4];
#pragma unroll
    for (int t = 0; t < 4; ++t) acc[t] = (f32x4)(0.f);
#pragma unroll
    for (int ks = 0; ks < 2; ++ks) {
        bf16x8 a = *(const bf16x8*)(&sCb[(wave * 16 + lrow) * 72 + ks * 32 + lk8]);
#pragma unroll
        for (int t = 0; t < 4; ++t) {
            bf16x8 bb = *(const bf16x8*)(&sP[(t * 16 + lrow) * 72 + ks * 32 + lk8]);
            acc[t] = __builtin_amdgcn_mfma_f32_16x16x32_bf16(a, bb, acc[t], 0, 0, 0);
        }
    }
#pragma unroll
    for (int t = 0; t < 4; ++t) {
#pragma unroll
        for (int r = 0; r < 4; ++r) {
            int l = wave * 16 + (lane >> 4) * 4 + r;
            int p = t * 16 + lrow;
            size_t idx = (size_t)(row0 + l) * D_INNERn + h * HEAD_DIMn + p;
            y[idx] += acc[t][r] * se[l];
        }
    }
}

// ---------------------------------------------------------------------------
// y_bf = bf16( RMSNorm(y * silu(z)) * norm_weight )
// ---------------------------------------------------------------------------
__global__ __launch_bounds__(256) void gate_norm_kernel(
    const float* __restrict__ y, const bf16* __restrict__ zb,
    const float* __restrict__ nw, bf16* __restrict__ y_bf) {
    const int row = blockIdx.x;
    const int tid = threadIdx.x;
    const size_t base = (size_t)row * D_INNERn + tid * 4;
    float4 yv = *(const float4*)(y + base);
    ushort4 zu = *(const ushort4*)((const unsigned short*)zb + base);
    float v0 = yv.x * silu_f(b2f(zu.x));
    float v1 = yv.y * silu_f(b2f(zu.y));
    float v2 = yv.z * silu_f(b2f(zu.z));
    float v3 = yv.w * silu_f(b2f(zu.w));
    float ss = v0 * v0 + v1 * v1 + v2 * v2 + v3 * v3;
#pragma unroll
    for (int o = 32; o > 0; o >>= 1) ss += __shfl_xor(ss, o);
    __shared__ float sred[4];
    if ((tid & 63) == 0) sred[tid >> 6] = ss;
    __syncthreads();
    float total = sred[0] + sred[1] + sred[2] + sred[3];
    float scale = rsqrtf(total * (1.0f / D_INNERn) + 1e-5f);
    float4 wv = *(const float4*)(nw + tid * 4);
    ushort4 o4;
    o4.x = f2b(v0 * scale * wv.x);
    o4.y = f2b(v1 * scale * wv.y);
    o4.z = f2b(v2 * scale * wv.z);
    o4.w = f2b(v3 * scale * wv.w);
    *(ushort4*)((unsigned short*)y_bf + base) = o4;
}

// ---------------------------------------------------------------------------
extern "C" void kernel_launch(void* const* d_in, const int* in_sizes, int n_in,
                              void* d_out, int out_size, void* d_ws, size_t ws_size,
                              hipStream_t stream) {
    (void)in_sizes; (void)n_in; (void)out_size; (void)ws_size;
    const float* x       = (const float*)d_in[0];
    const float* W_in    = (const float*)d_in[1];
    const float* ckx     = (const float*)d_in[2];
    const float* cbx     = (const float*)d_in[3];
    const float* ckz     = (const float*)d_in[4];
    const float* cbz     = (const float*)d_in[5];
    const float* W_xdbl  = (const float*)d_in[6];
    const float* dt_bias = (const float*)d_in[7];
    const float* A_log   = (const float*)d_in[8];
    const float* Dvec    = (const float*)d_in[9];
    const float* nw      = (const float*)d_in[10];
    const float* W_out   = (const float*)d_in[11];
    float* out = (float*)d_out;   // f32 output (round-6 verified)
    char* w = (char*)d_ws;

    // Workspace layout (bytes), total 212,877,312 — EXACTLY the proven size.
    bf16*  xz     = (bf16*)(w);               // [BL][2048] bf16 = 67,108,864
    float* y      = (float*)(w);              // alias: xz dead after conv
    bf16*  xi     = (bf16*)(w + 67108864);    // [BL][1024] bf16 = 33,554,432
    bf16*  zb     = (bf16*)(w + 100663296);   // [BL][1024] bf16 = 33,554,432
    char*  Sreg   = w + 134217728;            // 67,108,864 region, multi-use:
    float* S      = (float*)Sreg;             //   [4096][4096] f32 (SSD phase)
    bf16*  x_bf   = (bf16*)Sreg;              //   prologue: [BL][512] bf16 = 16.8M
    bf16*  W_in_T = (bf16*)(Sreg + 16777216); //   prologue: [2048][512] bf16 = 2.1M
    bf16*  W_xd_T = (bf16*)(Sreg + 18874368); //   prologue: [144][1024] bf16 = 0.3M
    bf16*  y_bf   = (bf16*)Sreg;              //   epilogue: [BL][1024] bf16 = 33.5M
    bf16*  W_o_T  = (bf16*)(Sreg + 33554432); //   epilogue: [512][1024] bf16 = 1.0M
    float* xdbl   = (float*)(w + 201326592);  // [BL][144] f32   =  9,437,184
    float* dtp    = (float*)(w + 210763776);  // [BL][16] f32    =  1,048,576
    float* acum   = (float*)(w + 211812352);  // [4096][64] f32  =  1,048,576
    float* rchunk = (float*)(w + 212860928);  // [4096] f32      =     16,384

    // 0. prologue converts (into S region — dead until ssd_chunk)
    cvt_f32_bf16<<<BL * D_MODELn / 1024, 256, 0, stream>>>(x, x_bf);
    transpose_cvt<<<dim3(2048 / 32, 512 / 32), 256, 0, stream>>>(W_in, W_in_T, 512, 2048);
    transpose_cvt<<<dim3(5, 1024 / 32), 256, 0, stream>>>(W_xdbl, W_xd_T, 1024, 144);
    // 1. xz = x @ W_in  (MFMA), store bf16
    gemm_mfma<bf16><<<dim3(2048 / 128, BL / 128), 256, 0, stream>>>(
        x_bf, W_in_T, xz, BL, 2048, D_MODELn);
    // 2. conv + silu -> xi, zb (bf16)
    conv_silu_kernel<<<BL, 256, 0, stream>>>(xz, ckx, cbx, ckz, cbz, xi, zb);
    // 3. x_dbl = xi @ W_xdbl  (MFMA), f32 out
    gemm_mfma<float><<<dim3(2, BL / 128), 256, 0, stream>>>(
        xi, W_xd_T, xdbl, BL, XDBL_N, D_INNERn);
    // 4. dt = softplus(...)
    dt_kernel<<<BL * N_HEADSn / 256, 256, 0, stream>>>(xdbl, dt_bias, dtp);
    // 5. SSD per-chunk (MFMA): Y_diag + states
    ssd_chunk_mfma<<<B_SZn * NCHUNK * N_HEADSn, 256, 0, stream>>>(
        xdbl, xi, dtp, A_log, Dvec, y, S, acum, rchunk);
    // 6. inter-chunk scan (in place)
    chunk_scan_kernel<<<B_SZn * N_HEADSn * 4096 / 256, 256, 0, stream>>>(S, rchunk);
    // 7. Y_off accumulate (MFMA)
    yoff_mfma<<<B_SZn * NCHUNK * N_HEADSn, 256, 0, stream>>>(xdbl, S, acum, y);
    // 8. epilogue: W_out^T (S dead after yoff), gate+norm -> y_bf
    transpose_cvt<<<dim3(512 / 32, 1024 / 32), 256, 0, stream>>>(W_out, W_o_T, 1024, 512);
    gate_norm_kernel<<<BL, 256, 0, stream>>>(y, zb, nw, y_bf);
    // 9. out = y @ W_out  (MFMA), store f32 to d_out
    gemm_mfma<float><<<dim3(512 / 128, BL / 128), 256, 0, stream>>>(
        y_bf, W_o_T, out, BL, D_MODELn, D_INNERn);
}

// Round 10
// 314.427 us; speedup vs baseline: 13.9730x; 1.2244x over previous
//
#include <hip/hip_runtime.h>
#include <hip/hip_bf16.h>
#include <cstdint>

#define B_SZn 4
#define SEQ_L 4096
#define D_MODELn 512
#define D_INNERn 1024
#define N_HEADSn 16
#define HEAD_DIMn 64
#define D_STATEn 64
#define CHUNKn 64
#define NCHUNK (SEQ_L / CHUNKn)          // 64
#define BL (B_SZn * SEQ_L)               // 16384
#define XDBL_N (N_HEADSn + 2 * D_STATEn) // 144

typedef __hip_bfloat16 bf16;
typedef __bf16 bf16x8 __attribute__((ext_vector_type(8)));
typedef float f32x4 __attribute__((ext_vector_type(4)));

__device__ __forceinline__ float silu_f(float v) {
    return v / (1.0f + expf(-v));
}
__device__ __forceinline__ float b2f(unsigned short u) {
    return __uint_as_float((unsigned)u << 16);
}
__device__ __forceinline__ unsigned short f2b(float f) {
    bf16 h = __float2bfloat16(f);
    return *(unsigned short*)&h;
}
__device__ __forceinline__ void stf(float* p, float v) { *p = v; }
__device__ __forceinline__ void stf(bf16* p, float v) { *p = __float2bfloat16(v); }

// async global->LDS 16B copy: LDS dest = wave-uniform base + lane*16 (HW),
// global src per-lane.  (m97/m193-proven pattern.)
__device__ __forceinline__ void async_copy16(void* lds, const void* g) {
    __builtin_amdgcn_global_load_lds(
        (const __attribute__((address_space(1))) unsigned int*)g,
        (__attribute__((address_space(3))) unsigned int*)lds, 16, 0, 0);
}

// ---------------------------------------------------------------------------
// x (f32) -> bf16 elementwise convert
// ---------------------------------------------------------------------------
__global__ __launch_bounds__(256) void cvt_f32_bf16(
    const float* __restrict__ in, bf16* __restrict__ out) {
    const int idx = blockIdx.x * 256 + threadIdx.x;
    float4 v = *(const float4*)(in + (size_t)idx * 4);
    ushort4 o;
    o.x = f2b(v.x); o.y = f2b(v.y); o.z = f2b(v.z); o.w = f2b(v.w);
    *(ushort4*)((unsigned short*)out + (size_t)idx * 4) = o;
}

// ---------------------------------------------------------------------------
// Transpose + convert: out[c][r] = bf16(in[r][c]).  in [R][C] f32.
// ---------------------------------------------------------------------------
__global__ __launch_bounds__(256) void transpose_cvt(
    const float* __restrict__ in, bf16* __restrict__ out, int R, int C) {
    __shared__ float t[32][33];
    const int bc = blockIdx.x * 32, br = blockIdx.y * 32;
    const int tx = threadIdx.x & 31, ty = threadIdx.x >> 5;  // ty 0..7
#pragma unroll
    for (int i = ty; i < 32; i += 8) {
        int r = br + i, c = bc + tx;
        t[i][tx] = (r < R && c < C) ? in[(size_t)r * C + c] : 0.f;
    }
    __syncthreads();
#pragma unroll
    for (int i = ty; i < 32; i += 8) {
        int c = bc + i, r = br + tx;
        if (c < C && r < R) out[(size_t)c * R + r] = __float2bfloat16(t[tx][i]);
    }
}

// ---------------------------------------------------------------------------
// bf16 MFMA GEMM: C[M,N] = A[M,K] @ Bt[N,K]^T.  128x128 tile, BK=32, 4 waves.
// m97 structure: linear LDS + global_load_lds width-16 staging.
// M multiple of 128; K multiple of 32; N bounds-checked on store (OOB B-rows
// read in-ws garbage that only feeds unstored output columns).
// ---------------------------------------------------------------------------
template <typename TO>
__global__ __launch_bounds__(256) void gemm_mfma(
    const bf16* __restrict__ A, const bf16* __restrict__ Bt,
    TO* __restrict__ C, int M, int N, int K) {
    __shared__ __align__(16) unsigned short Al[128 * 32];
    __shared__ __align__(16) unsigned short Bl[128 * 32];
    const int tid = threadIdx.x;
    const int wave = tid >> 6, lane = tid & 63;
    const int wm = (wave >> 1) * 64, wn = (wave & 1) * 64;
    const int bm = blockIdx.y * 128, bn = blockIdx.x * 128;
    f32x4 acc[4][4];
#pragma unroll
    for (int m = 0; m < 4; ++m)
#pragma unroll
        for (int n = 0; n < 4; ++n) acc[m][n] = (f32x4)(0.f);

    const int lrow = lane & 15, lk8 = (lane >> 4) * 8;
    const int srow = tid >> 2, sc8 = (tid & 3) * 8;  // staging seg: pass0 s=tid
    for (int k0 = 0; k0 < K; k0 += 32) {
        // A tile 128x32 bf16 = 8KB = 512 x 16B segs; seg s = p*256+tid,
        // row = s>>2, col8 = (tid&3)*8.  LDS linear: byte off = s*16.
        async_copy16((char*)Al + (size_t)(wave * 64) * 16,
                     A + (size_t)(bm + srow) * K + k0 + sc8);
        async_copy16((char*)Al + (size_t)(256 + wave * 64) * 16,
                     A + (size_t)(bm + 64 + srow) * K + k0 + sc8);
        async_copy16((char*)Bl + (size_t)(wave * 64) * 16,
                     Bt + (size_t)(bn + srow) * K + k0 + sc8);
        async_copy16((char*)Bl + (size_t)(256 + wave * 64) * 16,
                     Bt + (size_t)(bn + 64 + srow) * K + k0 + sc8);
        __syncthreads();   // compiler drains vmcnt before barrier
        bf16x8 af[4], bfr[4];
#pragma unroll
        for (int m = 0; m < 4; ++m)
            af[m] = *(const bf16x8*)(&Al[(wm + m * 16 + lrow) * 32 + lk8]);
#pragma unroll
        for (int n = 0; n < 4; ++n)
            bfr[n] = *(const bf16x8*)(&Bl[(wn + n * 16 + lrow) * 32 + lk8]);
#pragma unroll
        for (int m = 0; m < 4; ++m)
#pragma unroll
            for (int n = 0; n < 4; ++n)
                acc[m][n] = __builtin_amdgcn_mfma_f32_16x16x32_bf16(
                    af[m], bfr[n], acc[m][n], 0, 0, 0);
        __syncthreads();
    }
#pragma unroll
    for (int m = 0; m < 4; ++m) {
#pragma unroll
        for (int n = 0; n < 4; ++n) {
#pragma unroll
            for (int r = 0; r < 4; ++r) {
                int row = bm + wm + m * 16 + (lane >> 4) * 4 + r;
                int col = bn + wn + n * 16 + (lane & 15);
                if (row < M && col < N)
                    stf(&C[(size_t)row * N + col], acc[m][n][r]);
            }
        }
    }
}

// ---------------------------------------------------------------------------
// Depthwise conv (width 4, SAME: taps l-1..l+2) + bias + silu, both halves.
// ---------------------------------------------------------------------------
__global__ __launch_bounds__(256) void conv_silu_kernel(
    const bf16* __restrict__ xz,
    const float* __restrict__ kx, const float* __restrict__ bx,
    const float* __restrict__ kz, const float* __restrict__ bz,
    bf16* __restrict__ xi, bf16* __restrict__ zo) {
    const int idx = blockIdx.x * 256 + threadIdx.x;  // BL*256 threads
    const int d4 = (idx & 255) * 4;
    const int bl = idx >> 8;
    const int l = bl & (SEQ_L - 1);
    float ax[4], az[4];
#pragma unroll
    for (int j = 0; j < 4; ++j) { ax[j] = bx[d4 + j]; az[j] = bz[d4 + j]; }
#pragma unroll
    for (int k = 0; k < 4; ++k) {
        int ll = l - 1 + k;
        if (ll < 0 || ll >= SEQ_L) continue;
        const unsigned short* row =
            (const unsigned short*)(xz + (size_t)(bl + (ll - l)) * (2 * D_INNERn));
        ushort4 ux = *(const ushort4*)(row + d4);
        ushort4 uz = *(const ushort4*)(row + D_INNERn + d4);
        float4 wx = *(const float4*)(kx + k * D_INNERn + d4);
        float4 wz = *(const float4*)(kz + k * D_INNERn + d4);
        ax[0] += b2f(ux.x) * wx.x; ax[1] += b2f(ux.y) * wx.y;
        ax[2] += b2f(ux.z) * wx.z; ax[3] += b2f(ux.w) * wx.w;
        az[0] += b2f(uz.x) * wz.x; az[1] += b2f(uz.y) * wz.y;
        az[2] += b2f(uz.z) * wz.z; az[3] += b2f(uz.w) * wz.w;
    }
    ushort4 ox, oz;
    ox.x = f2b(silu_f(ax[0])); ox.y = f2b(silu_f(ax[1]));
    ox.z = f2b(silu_f(ax[2])); ox.w = f2b(silu_f(ax[3]));
    oz.x = f2b(silu_f(az[0])); oz.y = f2b(silu_f(az[1]));
    oz.z = f2b(silu_f(az[2])); oz.w = f2b(silu_f(az[3]));
    *(ushort4*)((unsigned short*)xi + (size_t)bl * D_INNERn + d4) = ox;
    *(ushort4*)((unsigned short*)zo + (size_t)bl * D_INNERn + d4) = oz;
}

// ---------------------------------------------------------------------------
// dt = softplus(x_dbl[..., :16] + dt_bias)
// ---------------------------------------------------------------------------
__global__ __launch_bounds__(256) void dt_kernel(
    const float* __restrict__ xdbl, const float* __restrict__ dt_bias,
    float* __restrict__ dtp) {
    const int idx = blockIdx.x * 256 + threadIdx.x;  // BL*16
    const int h = idx & 15;
    const int r = idx >> 4;
    float v = xdbl[(size_t)r * XDBL_N + h] + dt_bias[h];
    dtp[idx] = (v > 20.f) ? v : log1pf(expf(v));
}

// ---------------------------------------------------------------------------
// MFMA SSD chunk: per (b,c,h) block, 4 waves.  S output now bf16.
// ---------------------------------------------------------------------------
__global__ __launch_bounds__(256) void ssd_chunk_mfma(
    const float* __restrict__ xdbl, const bf16* __restrict__ xi,
    const float* __restrict__ dtp, const float* __restrict__ A_log,
    const float* __restrict__ Dvec,
    float* __restrict__ y, unsigned short* __restrict__ S,
    float* __restrict__ acum_g, float* __restrict__ rchunk) {
    __shared__ __align__(16) unsigned short sBb[64 * 72];  // B[s][n]
    __shared__ __align__(16) unsigned short sCb[64 * 72];  // C[l][n]
    __shared__ __align__(16) unsigned short sXT[64 * 72];  // X^T[p][s]
    __shared__ __align__(16) unsigned short sGb[64 * 72];  // G[l][s]
    __shared__ __align__(16) unsigned short sWB[64 * 72];  // (w·B)^T[n][s]
    __shared__ float sdtp[64], sacum[64], sw[64];
    const int bid = blockIdx.x;          // ((b*64 + c)*16 + h)
    const int h = bid & 15;
    const int bc = bid >> 4;
    const int c = bc & (NCHUNK - 1);
    const int b = bc >> 6;
    const int tid = threadIdx.x;
    const int wave = tid >> 6, lane = tid & 63;
    const int lrow = lane & 15, lk8 = (lane >> 4) * 8;
    const int row0 = b * SEQ_L + c * CHUNKn;
    const float Ah = -expf(A_log[h]);
    const float Dh = Dvec[h];

    if (tid < 64) sdtp[tid] = dtp[(size_t)(row0 + tid) * N_HEADSn + h];
    const unsigned short* xius = (const unsigned short*)xi;
#pragma unroll
    for (int it = 0; it < 16; ++it) {
        int e = tid + it * 256;
        int s = e >> 6, n = e & 63;
        const float* xr = xdbl + (size_t)(row0 + s) * XDBL_N + N_HEADSn;
        sBb[s * 72 + n] = f2b(xr[n]);
        sCb[s * 72 + n] = f2b(xr[D_STATEn + n]);
        sXT[n * 72 + s] = xius[(size_t)(row0 + s) * D_INNERn + h * HEAD_DIMn + n];
    }
    __syncthreads();
    // wave0: 64-lane inclusive scan of Ah*dt (hides under other waves' MFMA1)
    if (wave == 0) {
        float v = Ah * sdtp[lane];
#pragma unroll
        for (int o = 1; o < 64; o <<= 1) {
            float t = __shfl_up(v, o);
            if (lane >= o) v += t;
        }
        sacum[lane] = v;
        float last = __shfl(v, 63);
        sw[lane] = expf(last - v) * sdtp[lane];
        acum_g[(size_t)bid * 64 + lane] = v;
        if (lane == 63) rchunk[bid] = expf(v);
    }
    // MFMA1: Graw = C·B^T
    f32x4 acc1[4];
#pragma unroll
    for (int t = 0; t < 4; ++t) acc1[t] = (f32x4)(0.f);
#pragma unroll
    for (int ks = 0; ks < 2; ++ks) {
        bf16x8 a = *(const bf16x8*)(&sCb[(wave * 16 + lrow) * 72 + ks * 32 + lk8]);
#pragma unroll
        for (int t = 0; t < 4; ++t) {
            bf16x8 bb = *(const bf16x8*)(&sBb[(t * 16 + lrow) * 72 + ks * 32 + lk8]);
            acc1[t] = __builtin_amdgcn_mfma_f32_16x16x32_bf16(a, bb, acc1[t], 0, 0, 0);
        }
    }
    __syncthreads();   // sacum/sw ready
    // mask + decay-scale -> sGb
#pragma unroll
    for (int t = 0; t < 4; ++t) {
#pragma unroll
        for (int r = 0; r < 4; ++r) {
            int l = wave * 16 + (lane >> 4) * 4 + r;
            int s = t * 16 + lrow;
            float val = 0.f;
            if (l >= s) val = acc1[t][r] * expf(sacum[l] - sacum[s]) * sdtp[s];
            sGb[l * 72 + s] = f2b(val);
        }
    }
    // build (w·B)^T
#pragma unroll
    for (int it = 0; it < 16; ++it) {
        int e = tid + it * 256;
        int s = e >> 6, n = e & 63;
        sWB[n * 72 + s] = f2b(sw[s] * b2f(sBb[s * 72 + n]));
    }
    __syncthreads();
    // MFMA2: Y = G·X (+D·x).  MFMA3: S = X^T·(wB).
    f32x4 acc2[4], acc3[4];
#pragma unroll
    for (int t = 0; t < 4; ++t) { acc2[t] = (f32x4)(0.f); acc3[t] = (f32x4)(0.f); }
#pragma unroll
    for (int ks = 0; ks < 2; ++ks) {
        bf16x8 a2 = *(const bf16x8*)(&sGb[(wave * 16 + lrow) * 72 + ks * 32 + lk8]);
        bf16x8 a3 = *(const bf16x8*)(&sXT[(wave * 16 + lrow) * 72 + ks * 32 + lk8]);
#pragma unroll
        for (int t = 0; t < 4; ++t) {
            bf16x8 b2v = *(const bf16x8*)(&sXT[(t * 16 + lrow) * 72 + ks * 32 + lk8]);
            bf16x8 b3v = *(const bf16x8*)(&sWB[(t * 16 + lrow) * 72 + ks * 32 + lk8]);
            acc2[t] = __builtin_amdgcn_mfma_f32_16x16x32_bf16(a2, b2v, acc2[t], 0, 0, 0);
            acc3[t] = __builtin_amdgcn_mfma_f32_16x16x32_bf16(a3, b3v, acc3[t], 0, 0, 0);
        }
    }
#pragma unroll
    for (int t = 0; t < 4; ++t) {
#pragma unroll
        for (int r = 0; r < 4; ++r) {
            int rr = wave * 16 + (lane >> 4) * 4 + r;  // l for Y, p for S
            int cc = t * 16 + lrow;                    // p for Y, n for S
            float xv = b2f(sXT[cc * 72 + rr]);         // X[rr][cc]
            y[(size_t)(row0 + rr) * D_INNERn + h * HEAD_DIMn + cc] = acc2[t][r] + Dh * xv;
            S[(size_t)bid * 4096 + rr * 64 + cc] = f2b(acc3[t][r]);
        }
    }
}

// ---------------------------------------------------------------------------
// Inter-chunk scan (bf16 S, f32 running state): S[c] <- state ENTERING c.
// Each thread owns 2 consecutive (p,n) slots (uint = 2 bf16).
// ---------------------------------------------------------------------------
__global__ __launch_bounds__(256) void chunk_scan_kernel(
    unsigned short* __restrict__ S, const float* __restrict__ rchunk) {
    const int idx = blockIdx.x * 256 + threadIdx.x;  // BH * 2048
    const int pn2 = (idx & 2047) * 2;
    const int bh = idx >> 11;
    const int h = bh & 15;
    const int b = bh >> 4;
    float P0 = 0.f, P1 = 0.f;
    for (int c = 0; c < NCHUNK; ++c) {
        int bid = (b * NCHUNK + c) * N_HEADSn + h;
        size_t off = (size_t)bid * 4096 + pn2;
        unsigned int v = *(unsigned int*)(S + off);
        float s0 = b2f((unsigned short)(v & 0xffff));
        float s1 = b2f((unsigned short)(v >> 16));
        *(unsigned int*)(S + off) =
            (unsigned int)f2b(P0) | ((unsigned int)f2b(P1) << 16);
        float rc = rchunk[bid];
        P0 = rc * P0 + s0;
        P1 = rc * P1 + s1;
    }
}

// ---------------------------------------------------------------------------
// MFMA Y_off: y[l][p] += exp(acum[l]) * sum_n C[l][n] * P[p][n]   (P bf16)
// ---------------------------------------------------------------------------
__global__ __launch_bounds__(256) void yoff_mfma(
    const float* __restrict__ xdbl, const unsigned short* __restrict__ S,
    const float* __restrict__ acum_g, float* __restrict__ y) {
    __shared__ __align__(16) unsigned short sCb[64 * 72];
    __shared__ __align__(16) unsigned short sP[64 * 72];
    __shared__ float se[64];
    const int bid = blockIdx.x;
    const int h = bid & 15;
    const int bc = bid >> 4;
    const int c = bc & (NCHUNK - 1);
    const int b = bc >> 6;
    const int tid = threadIdx.x;
    const int wave = tid >> 6, lane = tid & 63;
    const int lrow = lane & 15, lk8 = (lane >> 4) * 8;
    const int row0 = b * SEQ_L + c * CHUNKn;
    if (tid < 64) se[tid] = expf(acum_g[(size_t)bid * 64 + tid]);
#pragma unroll
    for (int it = 0; it < 16; ++it) {
        int e = tid + it * 256;
        int r = e >> 6, n = e & 63;
        sCb[r * 72 + n] = f2b(xdbl[(size_t)(row0 + r) * XDBL_N + N_HEADSn + D_STATEn + n]);
        sP[r * 72 + n] = S[(size_t)bid * 4096 + e];
    }
    __syncthreads();
    f32x4 acc[4];
#pragma unroll
    for (int t = 0; t < 4; ++t) acc[t] = (f32x4)(0.f);
#pragma unroll
    for (int ks = 0; ks < 2; ++ks) {
        bf16x8 a = *(const bf16x8*)(&sCb[(wave * 16 + lrow) * 72 + ks * 32 + lk8]);
#pragma unroll
        for (int t = 0; t < 4; ++t) {
            bf16x8 bb = *(const bf16x8*)(&sP[(t * 16 + lrow) * 72 + ks * 32 + lk8]);
            acc[t] = __builtin_amdgcn_mfma_f32_16x16x32_bf16(a, bb, acc[t], 0, 0, 0);
        }
    }
#pragma unroll
    for (int t = 0; t < 4; ++t) {
#pragma unroll
        for (int r = 0; r < 4; ++r) {
            int l = wave * 16 + (lane >> 4) * 4 + r;
            int p = t * 16 + lrow;
            size_t idx = (size_t)(row0 + l) * D_INNERn + h * HEAD_DIMn + p;
            y[idx] += acc[t][r] * se[l];
        }
    }
}

// ---------------------------------------------------------------------------
// y_bf = bf16( RMSNorm(y * silu(z)) * norm_weight )
// ---------------------------------------------------------------------------
__global__ __launch_bounds__(256) void gate_norm_kernel(
    const float* __restrict__ y, const bf16* __restrict__ zb,
    const float* __restrict__ nw, bf16* __restrict__ y_bf) {
    const int row = blockIdx.x;
    const int tid = threadIdx.x;
    const size_t base = (size_t)row * D_INNERn + tid * 4;
    float4 yv = *(const float4*)(y + base);
    ushort4 zu = *(const ushort4*)((const unsigned short*)zb + base);
    float v0 = yv.x * silu_f(b2f(zu.x));
    float v1 = yv.y * silu_f(b2f(zu.y));
    float v2 = yv.z * silu_f(b2f(zu.z));
    float v3 = yv.w * silu_f(b2f(zu.w));
    float ss = v0 * v0 + v1 * v1 + v2 * v2 + v3 * v3;
#pragma unroll
    for (int o = 32; o > 0; o >>= 1) ss += __shfl_xor(ss, o);
    __shared__ float sred[4];
    if ((tid & 63) == 0) sred[tid >> 6] = ss;
    __syncthreads();
    float total = sred[0] + sred[1] + sred[2] + sred[3];
    float scale = rsqrtf(total * (1.0f / D_INNERn) + 1e-5f);
    float4 wv = *(const float4*)(nw + tid * 4);
    ushort4 o4;
    o4.x = f2b(v0 * scale * wv.x);
    o4.y = f2b(v1 * scale * wv.y);
    o4.z = f2b(v2 * scale * wv.z);
    o4.w = f2b(v3 * scale * wv.w);
    *(ushort4*)((unsigned short*)y_bf + base) = o4;
}

// ---------------------------------------------------------------------------
extern "C" void kernel_launch(void* const* d_in, const int* in_sizes, int n_in,
                              void* d_out, int out_size, void* d_ws, size_t ws_size,
                              hipStream_t stream) {
    (void)in_sizes; (void)n_in; (void)out_size; (void)ws_size;
    const float* x       = (const float*)d_in[0];
    const float* W_in    = (const float*)d_in[1];
    const float* ckx     = (const float*)d_in[2];
    const float* cbx     = (const float*)d_in[3];
    const float* ckz     = (const float*)d_in[4];
    const float* cbz     = (const float*)d_in[5];
    const float* W_xdbl  = (const float*)d_in[6];
    const float* dt_bias = (const float*)d_in[7];
    const float* A_log   = (const float*)d_in[8];
    const float* Dvec    = (const float*)d_in[9];
    const float* nw      = (const float*)d_in[10];
    const float* W_out   = (const float*)d_in[11];
    float* out = (float*)d_out;   // f32 output (round-6 verified)
    char* w = (char*)d_ws;

    // Workspace layout (bytes), total 212,877,312 — proven size.
    bf16*  xz     = (bf16*)(w);               // [BL][2048] bf16 = 67,108,864
    float* y      = (float*)(w);              // alias: xz dead after conv
    bf16*  xi     = (bf16*)(w + 67108864);    // [BL][1024] bf16 = 33,554,432
    bf16*  zb     = (bf16*)(w + 100663296);   // [BL][1024] bf16 = 33,554,432
    char*  Sreg   = w + 134217728;            // 67,108,864 region, multi-use:
    unsigned short* S = (unsigned short*)Sreg;//   [4096][4096] bf16 = 33.5M (SSD)
    bf16*  x_bf   = (bf16*)Sreg;              //   prologue: [BL][512] bf16 = 16.8M
    bf16*  W_in_T = (bf16*)(Sreg + 16777216); //   prologue: [2048][512] bf16 = 2.1M
    bf16*  W_xd_T = (bf16*)(Sreg + 18874368); //   prologue: [144][1024] bf16 = 0.3M
    bf16*  y_bf   = (bf16*)Sreg;              //   epilogue: [BL][1024] bf16 = 33.5M
    bf16*  W_o_T  = (bf16*)(Sreg + 33554432); //   epilogue: [512][1024] bf16 = 1.0M
    float* xdbl   = (float*)(w + 201326592);  // [BL][144] f32   =  9,437,184
    float* dtp    = (float*)(w + 210763776);  // [BL][16] f32    =  1,048,576
    float* acum   = (float*)(w + 211812352);  // [4096][64] f32  =  1,048,576
    float* rchunk = (float*)(w + 212860928);  // [4096] f32      =     16,384

    // 0. prologue converts (into S region — dead until ssd_chunk)
    cvt_f32_bf16<<<BL * D_MODELn / 1024, 256, 0, stream>>>(x, x_bf);
    transpose_cvt<<<dim3(2048 / 32, 512 / 32), 256, 0, stream>>>(W_in, W_in_T, 512, 2048);
    transpose_cvt<<<dim3(5, 1024 / 32), 256, 0, stream>>>(W_xdbl, W_xd_T, 1024, 144);
    // 1. xz = x @ W_in  (MFMA + global_load_lds), store bf16
    gemm_mfma<bf16><<<dim3(2048 / 128, BL / 128), 256, 0, stream>>>(
        x_bf, W_in_T, xz, BL, 2048, D_MODELn);
    // 2. conv + silu -> xi, zb (bf16)
    conv_silu_kernel<<<BL, 256, 0, stream>>>(xz, ckx, cbx, ckz, cbz, xi, zb);
    // 3. x_dbl = xi @ W_xdbl  (MFMA), f32 out
    gemm_mfma<float><<<dim3(2, BL / 128), 256, 0, stream>>>(
        xi, W_xd_T, xdbl, BL, XDBL_N, D_INNERn);
    // 4. dt = softplus(...)
    dt_kernel<<<BL * N_HEADSn / 256, 256, 0, stream>>>(xdbl, dt_bias, dtp);
    // 5. SSD per-chunk (MFMA): Y_diag + states (S bf16)
    ssd_chunk_mfma<<<B_SZn * NCHUNK * N_HEADSn, 256, 0, stream>>>(
        xdbl, xi, dtp, A_log, Dvec, y, S, acum, rchunk);
    // 6. inter-chunk scan (in place, bf16)
    chunk_scan_kernel<<<B_SZn * N_HEADSn * 2048 / 256, 256, 0, stream>>>(S, rchunk);
    // 7. Y_off accumulate (MFMA)
    yoff_mfma<<<B_SZn * NCHUNK * N_HEADSn, 256, 0, stream>>>(xdbl, S, acum, y);
    // 8. epilogue: W_out^T (S dead after yoff), gate+norm -> y_bf
    transpose_cvt<<<dim3(512 / 32, 1024 / 32), 256, 0, stream>>>(W_out, W_o_T, 1024, 512);
    gate_norm_kernel<<<BL, 256, 0, stream>>>(y, zb, nw, y_bf);
    // 9. out = y @ W_out  (MFMA), store f32 to d_out
    gemm_mfma<float><<<dim3(512 / 128, BL / 128), 256, 0, stream>>>(
        y_bf, W_o_T, out, BL, D_MODELn, D_INNERn);
}

// Round 11
// 279.191 us; speedup vs baseline: 15.7365x; 1.1262x over previous
//
#include <hip/hip_runtime.h>
#include <hip/hip_bf16.h>
#include <cstdint>

#define B_SZn 4
#define SEQ_L 4096
#define D_MODELn 512
#define D_INNERn 1024
#define N_HEADSn 16
#define HEAD_DIMn 64
#define D_STATEn 64
#define CHUNKn 64
#define NCHUNK (SEQ_L / CHUNKn)          // 64
#define BL (B_SZn * SEQ_L)               // 16384
#define XDBL_N (N_HEADSn + 2 * D_STATEn) // 144

typedef __hip_bfloat16 bf16;
typedef __bf16 bf16x8 __attribute__((ext_vector_type(8)));
typedef float f32x4 __attribute__((ext_vector_type(4)));

__device__ __forceinline__ float silu_f(float v) {
    return v / (1.0f + expf(-v));
}
__device__ __forceinline__ float b2f(unsigned short u) {
    return __uint_as_float((unsigned)u << 16);
}
__device__ __forceinline__ unsigned short f2b(float f) {
    bf16 h = __float2bfloat16(f);
    return *(unsigned short*)&h;
}
__device__ __forceinline__ void stf(float* p, float v) { *p = v; }
__device__ __forceinline__ void stf(bf16* p, float v) { *p = __float2bfloat16(v); }

// async global->LDS 16B copy: LDS dest = wave-uniform base + lane*16 (HW),
// global src per-lane.  (m97/m193-proven pattern.)
__device__ __forceinline__ void async_copy16(void* lds, const void* g) {
    __builtin_amdgcn_global_load_lds(
        (const __attribute__((address_space(1))) unsigned int*)g,
        (__attribute__((address_space(3))) unsigned int*)lds, 16, 0, 0);
}

// ---------------------------------------------------------------------------
// x (f32) -> bf16 elementwise convert
// ---------------------------------------------------------------------------
__global__ __launch_bounds__(256) void cvt_f32_bf16(
    const float* __restrict__ in, bf16* __restrict__ out) {
    const int idx = blockIdx.x * 256 + threadIdx.x;
    float4 v = *(const float4*)(in + (size_t)idx * 4);
    ushort4 o;
    o.x = f2b(v.x); o.y = f2b(v.y); o.z = f2b(v.z); o.w = f2b(v.w);
    *(ushort4*)((unsigned short*)out + (size_t)idx * 4) = o;
}

// ---------------------------------------------------------------------------
// Transpose + convert: out[c][r] = bf16(in[r][c]).  in [R][C] f32.
// ---------------------------------------------------------------------------
__global__ __launch_bounds__(256) void transpose_cvt(
    const float* __restrict__ in, bf16* __restrict__ out, int R, int C) {
    __shared__ float t[32][33];
    const int bc = blockIdx.x * 32, br = blockIdx.y * 32;
    const int tx = threadIdx.x & 31, ty = threadIdx.x >> 5;  // ty 0..7
#pragma unroll
    for (int i = ty; i < 32; i += 8) {
        int r = br + i, c = bc + tx;
        t[i][tx] = (r < R && c < C) ? in[(size_t)r * C + c] : 0.f;
    }
    __syncthreads();
#pragma unroll
    for (int i = ty; i < 32; i += 8) {
        int c = bc + i, r = br + tx;
        if (c < C && r < R) out[(size_t)c * R + r] = __float2bfloat16(t[tx][i]);
    }
}

// ---------------------------------------------------------------------------
// bf16 MFMA GEMM: C[M,N] = A[M,K] @ Bt[N,K]^T.  128x128 tile, BK=64 (two
// 32-wide half-subtiles so global_load_lds stays linear), 4 waves.
// XCD-aware block swizzle (T1): contiguous grid chunk per XCD for L2 reuse.
// M mult of 128, K mult of 64; N bounds-checked on store (OOB Bt rows read
// in-workspace garbage that only feeds unstored columns).
// ---------------------------------------------------------------------------
template <typename TO>
__global__ __launch_bounds__(256) void gemm_mfma(
    const bf16* __restrict__ A, const bf16* __restrict__ Bt,
    TO* __restrict__ C, int M, int N, int K) {
    __shared__ __align__(16) unsigned short Al[2][128 * 32];
    __shared__ __align__(16) unsigned short Bl[2][128 * 32];
    const int tid = threadIdx.x;
    const int wave = tid >> 6, lane = tid & 63;
    const int wm = (wave >> 1) * 64, wn = (wave & 1) * 64;
    // XCD swizzle: nwg % 8 == 0 for all our launches (2048 / 256 / 512)
    int lin = blockIdx.y * gridDim.x + blockIdx.x;
    const int nwg = gridDim.x * gridDim.y;
    if ((nwg & 7) == 0) lin = (lin & 7) * (nwg >> 3) + (lin >> 3);
    const int bm = (lin / gridDim.x) * 128, bn = (lin % gridDim.x) * 128;
    f32x4 acc[4][4];
#pragma unroll
    for (int m = 0; m < 4; ++m)
#pragma unroll
        for (int n = 0; n < 4; ++n) acc[m][n] = (f32x4)(0.f);

    const int lrow = lane & 15, lk8 = (lane >> 4) * 8;
    const int srow = tid >> 2, sc8 = (tid & 3) * 8;
    for (int k0 = 0; k0 < K; k0 += 64) {
#pragma unroll
        for (int h = 0; h < 2; ++h) {
            const int kh = k0 + h * 32;
            async_copy16((char*)&Al[h][0] + (size_t)(wave * 64) * 16,
                         A + (size_t)(bm + srow) * K + kh + sc8);
            async_copy16((char*)&Al[h][0] + (size_t)(256 + wave * 64) * 16,
                         A + (size_t)(bm + 64 + srow) * K + kh + sc8);
            async_copy16((char*)&Bl[h][0] + (size_t)(wave * 64) * 16,
                         Bt + (size_t)(bn + srow) * K + kh + sc8);
            async_copy16((char*)&Bl[h][0] + (size_t)(256 + wave * 64) * 16,
                         Bt + (size_t)(bn + 64 + srow) * K + kh + sc8);
        }
        __syncthreads();   // compiler drains vmcnt before barrier
#pragma unroll
        for (int h = 0; h < 2; ++h) {
            bf16x8 af[4], bfr[4];
#pragma unroll
            for (int m = 0; m < 4; ++m)
                af[m] = *(const bf16x8*)(&Al[h][(wm + m * 16 + lrow) * 32 + lk8]);
#pragma unroll
            for (int n = 0; n < 4; ++n)
                bfr[n] = *(const bf16x8*)(&Bl[h][(wn + n * 16 + lrow) * 32 + lk8]);
#pragma unroll
            for (int m = 0; m < 4; ++m)
#pragma unroll
                for (int n = 0; n < 4; ++n)
                    acc[m][n] = __builtin_amdgcn_mfma_f32_16x16x32_bf16(
                        af[m], bfr[n], acc[m][n], 0, 0, 0);
        }
        __syncthreads();
    }
#pragma unroll
    for (int m = 0; m < 4; ++m) {
#pragma unroll
        for (int n = 0; n < 4; ++n) {
#pragma unroll
            for (int r = 0; r < 4; ++r) {
                int row = bm + wm + m * 16 + (lane >> 4) * 4 + r;
                int col = bn + wn + n * 16 + (lane & 15);
                if (row < M && col < N)
                    stf(&C[(size_t)row * N + col], acc[m][n][r]);
            }
        }
    }
}

// ---------------------------------------------------------------------------
// Depthwise conv (width 4, SAME: taps l-1..l+2) + bias + silu, both halves.
// ---------------------------------------------------------------------------
__global__ __launch_bounds__(256) void conv_silu_kernel(
    const bf16* __restrict__ xz,
    const float* __restrict__ kx, const float* __restrict__ bx,
    const float* __restrict__ kz, const float* __restrict__ bz,
    bf16* __restrict__ xi, bf16* __restrict__ zo) {
    const int idx = blockIdx.x * 256 + threadIdx.x;  // BL*256 threads
    const int d4 = (idx & 255) * 4;
    const int bl = idx >> 8;
    const int l = bl & (SEQ_L - 1);
    float ax[4], az[4];
#pragma unroll
    for (int j = 0; j < 4; ++j) { ax[j] = bx[d4 + j]; az[j] = bz[d4 + j]; }
#pragma unroll
    for (int k = 0; k < 4; ++k) {
        int ll = l - 1 + k;
        if (ll < 0 || ll >= SEQ_L) continue;
        const unsigned short* row =
            (const unsigned short*)(xz + (size_t)(bl + (ll - l)) * (2 * D_INNERn));
        ushort4 ux = *(const ushort4*)(row + d4);
        ushort4 uz = *(const ushort4*)(row + D_INNERn + d4);
        float4 wx = *(const float4*)(kx + k * D_INNERn + d4);
        float4 wz = *(const float4*)(kz + k * D_INNERn + d4);
        ax[0] += b2f(ux.x) * wx.x; ax[1] += b2f(ux.y) * wx.y;
        ax[2] += b2f(ux.z) * wx.z; ax[3] += b2f(ux.w) * wx.w;
        az[0] += b2f(uz.x) * wz.x; az[1] += b2f(uz.y) * wz.y;
        az[2] += b2f(uz.z) * wz.z; az[3] += b2f(uz.w) * wz.w;
    }
    ushort4 ox, oz;
    ox.x = f2b(silu_f(ax[0])); ox.y = f2b(silu_f(ax[1]));
    ox.z = f2b(silu_f(ax[2])); ox.w = f2b(silu_f(ax[3]));
    oz.x = f2b(silu_f(az[0])); oz.y = f2b(silu_f(az[1]));
    oz.z = f2b(silu_f(az[2])); oz.w = f2b(silu_f(az[3]));
    *(ushort4*)((unsigned short*)xi + (size_t)bl * D_INNERn + d4) = ox;
    *(ushort4*)((unsigned short*)zo + (size_t)bl * D_INNERn + d4) = oz;
}

// ---------------------------------------------------------------------------
// dt = softplus(x_dbl[..., :16] + dt_bias)   (xdbl now bf16)
// ---------------------------------------------------------------------------
__global__ __launch_bounds__(256) void dt_kernel(
    const unsigned short* __restrict__ xdbl, const float* __restrict__ dt_bias,
    float* __restrict__ dtp) {
    const int idx = blockIdx.x * 256 + threadIdx.x;  // BL*16
    const int h = idx & 15;
    const int r = idx >> 4;
    float v = b2f(xdbl[(size_t)r * XDBL_N + h]) + dt_bias[h];
    dtp[idx] = (v > 20.f) ? v : log1pf(expf(v));
}

// ---------------------------------------------------------------------------
// MFMA SSD chunk: per (b,c,h) block, 4 waves.  xdbl bf16; y, S bf16 out.
// ---------------------------------------------------------------------------
__global__ __launch_bounds__(256) void ssd_chunk_mfma(
    const unsigned short* __restrict__ xdbl, const bf16* __restrict__ xi,
    const float* __restrict__ dtp, const float* __restrict__ A_log,
    const float* __restrict__ Dvec,
    unsigned short* __restrict__ y, unsigned short* __restrict__ S,
    float* __restrict__ acum_g, float* __restrict__ rchunk) {
    __shared__ __align__(16) unsigned short sBb[64 * 72];  // B[s][n]
    __shared__ __align__(16) unsigned short sCb[64 * 72];  // C[l][n]
    __shared__ __align__(16) unsigned short sXT[64 * 72];  // X^T[p][s]
    __shared__ __align__(16) unsigned short sGb[64 * 72];  // G[l][s]
    __shared__ __align__(16) unsigned short sWB[64 * 72];  // (w·B)^T[n][s]
    __shared__ float sdtp[64], sacum[64], sw[64];
    const int bid = blockIdx.x;          // ((b*64 + c)*16 + h)
    const int h = bid & 15;
    const int bc = bid >> 4;
    const int c = bc & (NCHUNK - 1);
    const int b = bc >> 6;
    const int tid = threadIdx.x;
    const int wave = tid >> 6, lane = tid & 63;
    const int lrow = lane & 15, lk8 = (lane >> 4) * 8;
    const int row0 = b * SEQ_L + c * CHUNKn;
    const float Ah = -expf(A_log[h]);
    const float Dh = Dvec[h];

    if (tid < 64) sdtp[tid] = dtp[(size_t)(row0 + tid) * N_HEADSn + h];
    const unsigned short* xius = (const unsigned short*)xi;
#pragma unroll
    for (int it = 0; it < 16; ++it) {
        int e = tid + it * 256;
        int s = e >> 6, n = e & 63;
        const unsigned short* xr = xdbl + (size_t)(row0 + s) * XDBL_N + N_HEADSn;
        sBb[s * 72 + n] = xr[n];
        sCb[s * 72 + n] = xr[D_STATEn + n];
        sXT[n * 72 + s] = xius[(size_t)(row0 + s) * D_INNERn + h * HEAD_DIMn + n];
    }
    __syncthreads();
    // wave0: 64-lane inclusive scan of Ah*dt (hides under other waves' MFMA1)
    if (wave == 0) {
        float v = Ah * sdtp[lane];
#pragma unroll
        for (int o = 1; o < 64; o <<= 1) {
            float t = __shfl_up(v, o);
            if (lane >= o) v += t;
        }
        sacum[lane] = v;
        float last = __shfl(v, 63);
        sw[lane] = expf(last - v) * sdtp[lane];
        acum_g[(size_t)bid * 64 + lane] = v;
        if (lane == 63) rchunk[bid] = expf(v);
    }
    // MFMA1: Graw = C·B^T
    f32x4 acc1[4];
#pragma unroll
    for (int t = 0; t < 4; ++t) acc1[t] = (f32x4)(0.f);
#pragma unroll
    for (int ks = 0; ks < 2; ++ks) {
        bf16x8 a = *(const bf16x8*)(&sCb[(wave * 16 + lrow) * 72 + ks * 32 + lk8]);
#pragma unroll
        for (int t = 0; t < 4; ++t) {
            bf16x8 bb = *(const bf16x8*)(&sBb[(t * 16 + lrow) * 72 + ks * 32 + lk8]);
            acc1[t] = __builtin_amdgcn_mfma_f32_16x16x32_bf16(a, bb, acc1[t], 0, 0, 0);
        }
    }
    __syncthreads();   // sacum/sw ready
    // mask + decay-scale -> sGb
#pragma unroll
    for (int t = 0; t < 4; ++t) {
#pragma unroll
        for (int r = 0; r < 4; ++r) {
            int l = wave * 16 + (lane >> 4) * 4 + r;
            int s = t * 16 + lrow;
            float val = 0.f;
            if (l >= s) val = acc1[t][r] * expf(sacum[l] - sacum[s]) * sdtp[s];
            sGb[l * 72 + s] = f2b(val);
        }
    }
    // build (w·B)^T
#pragma unroll
    for (int it = 0; it < 16; ++it) {
        int e = tid + it * 256;
        int s = e >> 6, n = e & 63;
        sWB[n * 72 + s] = f2b(sw[s] * b2f(sBb[s * 72 + n]));
    }
    __syncthreads();
    // MFMA2: Y = G·X (+D·x).  MFMA3: S = X^T·(wB).
    f32x4 acc2[4], acc3[4];
#pragma unroll
    for (int t = 0; t < 4; ++t) { acc2[t] = (f32x4)(0.f); acc3[t] = (f32x4)(0.f); }
#pragma unroll
    for (int ks = 0; ks < 2; ++ks) {
        bf16x8 a2 = *(const bf16x8*)(&sGb[(wave * 16 + lrow) * 72 + ks * 32 + lk8]);
        bf16x8 a3 = *(const bf16x8*)(&sXT[(wave * 16 + lrow) * 72 + ks * 32 + lk8]);
#pragma unroll
        for (int t = 0; t < 4; ++t) {
            bf16x8 b2v = *(const bf16x8*)(&sXT[(t * 16 + lrow) * 72 + ks * 32 + lk8]);
            bf16x8 b3v = *(const bf16x8*)(&sWB[(t * 16 + lrow) * 72 + ks * 32 + lk8]);
            acc2[t] = __builtin_amdgcn_mfma_f32_16x16x32_bf16(a2, b2v, acc2[t], 0, 0, 0);
            acc3[t] = __builtin_amdgcn_mfma_f32_16x16x32_bf16(a3, b3v, acc3[t], 0, 0, 0);
        }
    }
#pragma unroll
    for (int t = 0; t < 4; ++t) {
#pragma unroll
        for (int r = 0; r < 4; ++r) {
            int rr = wave * 16 + (lane >> 4) * 4 + r;  // l for Y, p for S
            int cc = t * 16 + lrow;                    // p for Y, n for S
            float xv = b2f(sXT[cc * 72 + rr]);         // X[rr][cc]
            y[(size_t)(row0 + rr) * D_INNERn + h * HEAD_DIMn + cc] =
                f2b(acc2[t][r] + Dh * xv);
            S[(size_t)bid * 4096 + rr * 64 + cc] = f2b(acc3[t][r]);
        }
    }
}

// ---------------------------------------------------------------------------
// Inter-chunk scan (bf16 S, f32 running state): S[c] <- state ENTERING c.
// ---------------------------------------------------------------------------
__global__ __launch_bounds__(256) void chunk_scan_kernel(
    unsigned short* __restrict__ S, const float* __restrict__ rchunk) {
    const int idx = blockIdx.x * 256 + threadIdx.x;  // BH * 2048
    const int pn2 = (idx & 2047) * 2;
    const int bh = idx >> 11;
    const int h = bh & 15;
    const int b = bh >> 4;
    float P0 = 0.f, P1 = 0.f;
    for (int c = 0; c < NCHUNK; ++c) {
        int bid = (b * NCHUNK + c) * N_HEADSn + h;
        size_t off = (size_t)bid * 4096 + pn2;
        unsigned int v = *(unsigned int*)(S + off);
        float s0 = b2f((unsigned short)(v & 0xffff));
        float s1 = b2f((unsigned short)(v >> 16));
        *(unsigned int*)(S + off) =
            (unsigned int)f2b(P0) | ((unsigned int)f2b(P1) << 16);
        float rc = rchunk[bid];
        P0 = rc * P0 + s0;
        P1 = rc * P1 + s1;
    }
}

// ---------------------------------------------------------------------------
// MFMA Y_off: y[l][p] += exp(acum[l]) * sum_n C[l][n] * P[p][n]
// xdbl bf16, P bf16, y bf16 RMW.
// ---------------------------------------------------------------------------
__global__ __launch_bounds__(256) void yoff_mfma(
    const unsigned short* __restrict__ xdbl, const unsigned short* __restrict__ S,
    const float* __restrict__ acum_g, unsigned short* __restrict__ y) {
    __shared__ __align__(16) unsigned short sCb[64 * 72];
    __shared__ __align__(16) unsigned short sP[64 * 72];
    __shared__ float se[64];
    const int bid = blockIdx.x;
    const int h = bid & 15;
    const int bc = bid >> 4;
    const int c = bc & (NCHUNK - 1);
    const int b = bc >> 6;
    const int tid = threadIdx.x;
    const int wave = tid >> 6, lane = tid & 63;
    const int lrow = lane & 15, lk8 = (lane >> 4) * 8;
    const int row0 = b * SEQ_L + c * CHUNKn;
    if (tid < 64) se[tid] = expf(acum_g[(size_t)bid * 64 + tid]);
#pragma unroll
    for (int it = 0; it < 16; ++it) {
        int e = tid + it * 256;
        int r = e >> 6, n = e & 63;
        sCb[r * 72 + n] = xdbl[(size_t)(row0 + r) * XDBL_N + N_HEADSn + D_STATEn + n];
        sP[r * 72 + n] = S[(size_t)bid * 4096 + e];
    }
    __syncthreads();
    f32x4 acc[4];
#pragma unroll
    for (int t = 0; t < 4; ++t) acc[t] = (f32x4)(0.f);
#pragma unroll
    for (int ks = 0; ks < 2; ++ks) {
        bf16x8 a = *(const bf16x8*)(&sCb[(wave * 16 + lrow) * 72 + ks * 32 + lk8]);
#pragma unroll
        for (int t = 0; t < 4; ++t) {
            bf16x8 bb = *(const bf16x8*)(&sP[(t * 16 + lrow) * 72 + ks * 32 + lk8]);
            acc[t] = __builtin_amdgcn_mfma_f32_16x16x32_bf16(a, bb, acc[t], 0, 0, 0);
        }
    }
#pragma unroll
    for (int t = 0; t < 4; ++t) {
#pragma unroll
        for (int r = 0; r < 4; ++r) {
            int l = wave * 16 + (lane >> 4) * 4 + r;
            int p = t * 16 + lrow;
            size_t idx = (size_t)(row0 + l) * D_INNERn + h * HEAD_DIMn + p;
            y[idx] = f2b(b2f(y[idx]) + acc[t][r] * se[l]);
        }
    }
}

// ---------------------------------------------------------------------------
// y_bf = bf16( RMSNorm(y * silu(z)) * norm_weight )   (y input bf16 now)
// ---------------------------------------------------------------------------
__global__ __launch_bounds__(256) void gate_norm_kernel(
    const unsigned short* __restrict__ y, const bf16* __restrict__ zb,
    const float* __restrict__ nw, bf16* __restrict__ y_bf) {
    const int row = blockIdx.x;
    const int tid = threadIdx.x;
    const size_t base = (size_t)row * D_INNERn + tid * 4;
    ushort4 yu = *(const ushort4*)(y + base);
    ushort4 zu = *(const ushort4*)((const unsigned short*)zb + base);
    float v0 = b2f(yu.x) * silu_f(b2f(zu.x));
    float v1 = b2f(yu.y) * silu_f(b2f(zu.y));
    float v2 = b2f(yu.z) * silu_f(b2f(zu.z));
    float v3 = b2f(yu.w) * silu_f(b2f(zu.w));
    float ss = v0 * v0 + v1 * v1 + v2 * v2 + v3 * v3;
#pragma unroll
    for (int o = 32; o > 0; o >>= 1) ss += __shfl_xor(ss, o);
    __shared__ float sred[4];
    if ((tid & 63) == 0) sred[tid >> 6] = ss;
    __syncthreads();
    float total = sred[0] + sred[1] + sred[2] + sred[3];
    float scale = rsqrtf(total * (1.0f / D_INNERn) + 1e-5f);
    float4 wv = *(const float4*)(nw + tid * 4);
    ushort4 o4;
    o4.x = f2b(v0 * scale * wv.x);
    o4.y = f2b(v1 * scale * wv.y);
    o4.z = f2b(v2 * scale * wv.z);
    o4.w = f2b(v3 * scale * wv.w);
    *(ushort4*)((unsigned short*)y_bf + base) = o4;
}

// ---------------------------------------------------------------------------
extern "C" void kernel_launch(void* const* d_in, const int* in_sizes, int n_in,
                              void* d_out, int out_size, void* d_ws, size_t ws_size,
                              hipStream_t stream) {
    (void)in_sizes; (void)n_in; (void)out_size; (void)ws_size;
    const float* x       = (const float*)d_in[0];
    const float* W_in    = (const float*)d_in[1];
    const float* ckx     = (const float*)d_in[2];
    const float* cbx     = (const float*)d_in[3];
    const float* ckz     = (const float*)d_in[4];
    const float* cbz     = (const float*)d_in[5];
    const float* W_xdbl  = (const float*)d_in[6];
    const float* dt_bias = (const float*)d_in[7];
    const float* A_log   = (const float*)d_in[8];
    const float* Dvec    = (const float*)d_in[9];
    const float* nw      = (const float*)d_in[10];
    const float* W_out   = (const float*)d_in[11];
    float* out = (float*)d_out;   // f32 output (round-6 verified)
    char* w = (char*)d_ws;

    // Workspace layout (bytes), total 212,877,312 — proven size.
    bf16*  xz     = (bf16*)(w);               // [BL][2048] bf16 = 67,108,864
    unsigned short* y = (unsigned short*)(w); // alias: bf16 [BL][1024] (xz dead)
    bf16*  xi     = (bf16*)(w + 67108864);    // [BL][1024] bf16 = 33,554,432
    bf16*  zb     = (bf16*)(w + 100663296);   // [BL][1024] bf16 = 33,554,432
    char*  Sreg   = w + 134217728;            // 67,108,864 region, multi-use:
    unsigned short* S = (unsigned short*)Sreg;//   [4096][4096] bf16 = 33.5M (SSD)
    bf16*  x_bf   = (bf16*)Sreg;              //   prologue: [BL][512] bf16 = 16.8M
    bf16*  W_in_T = (bf16*)(Sreg + 16777216); //   prologue: [2048][512] bf16 = 2.1M
    bf16*  W_xd_T = (bf16*)(Sreg + 18874368); //   prologue: [144][1024] bf16 = 0.3M
    bf16*  y_bf   = (bf16*)Sreg;              //   epilogue: [BL][1024] bf16 = 33.5M
    bf16*  W_o_T  = (bf16*)(Sreg + 33554432); //   epilogue: [512][1024] bf16 = 1.0M
    unsigned short* xdbl = (unsigned short*)(w + 201326592);  // [BL][144] bf16 = 4.7M
    float* dtp    = (float*)(w + 210763776);  // [BL][16] f32    =  1,048,576
    float* acum   = (float*)(w + 211812352);  // [4096][64] f32  =  1,048,576
    float* rchunk = (float*)(w + 212860928);  // [4096] f32      =     16,384

    // 0. prologue converts (into S region — dead until ssd_chunk)
    cvt_f32_bf16<<<BL * D_MODELn / 1024, 256, 0, stream>>>(x, x_bf);
    transpose_cvt<<<dim3(2048 / 32, 512 / 32), 256, 0, stream>>>(W_in, W_in_T, 512, 2048);
    transpose_cvt<<<dim3(5, 1024 / 32), 256, 0, stream>>>(W_xdbl, W_xd_T, 1024, 144);
    // 1. xz = x @ W_in  (MFMA, BK=64, XCD swizzle), store bf16
    gemm_mfma<bf16><<<dim3(2048 / 128, BL / 128), 256, 0, stream>>>(
        x_bf, W_in_T, xz, BL, 2048, D_MODELn);
    // 2. conv + silu -> xi, zb (bf16)
    conv_silu_kernel<<<BL, 256, 0, stream>>>(xz, ckx, cbx, ckz, cbz, xi, zb);
    // 3. x_dbl = xi @ W_xdbl  (MFMA), bf16 out
    gemm_mfma<bf16><<<dim3(2, BL / 128), 256, 0, stream>>>(
        xi, W_xd_T, (bf16*)xdbl, BL, XDBL_N, D_INNERn);
    // 4. dt = softplus(...)
    dt_kernel<<<BL * N_HEADSn / 256, 256, 0, stream>>>(xdbl, dt_bias, dtp);
    // 5. SSD per-chunk (MFMA): Y_diag + states (y, S bf16)
    ssd_chunk_mfma<<<B_SZn * NCHUNK * N_HEADSn, 256, 0, stream>>>(
        xdbl, xi, dtp, A_log, Dvec, y, S, acum, rchunk);
    // 6. inter-chunk scan (in place, bf16)
    chunk_scan_kernel<<<B_SZn * N_HEADSn * 2048 / 256, 256, 0, stream>>>(S, rchunk);
    // 7. Y_off accumulate (MFMA, bf16 RMW)
    yoff_mfma<<<B_SZn * NCHUNK * N_HEADSn, 256, 0, stream>>>(xdbl, S, acum, y);
    // 8. epilogue: W_out^T (S dead after yoff), gate+norm -> y_bf
    transpose_cvt<<<dim3(512 / 32, 1024 / 32), 256, 0, stream>>>(W_out, W_o_T, 1024, 512);
    gate_norm_kernel<<<BL, 256, 0, stream>>>(y, zb, nw, y_bf);
    // 9. out = y @ W_out  (MFMA), store f32 to d_out
    gemm_mfma<float><<<dim3(512 / 128, BL / 128), 256, 0, stream>>>(
        y_bf, W_o_T, out, BL, D_MODELn, D_INNERn);
}

// Round 12
// 257.797 us; speedup vs baseline: 17.0424x; 1.0830x over previous
//
#include <hip/hip_runtime.h>
#include <hip/hip_bf16.h>
#include <cstdint>

#define B_SZn 4
#define SEQ_L 4096
#define D_MODELn 512
#define D_INNERn 1024
#define N_HEADSn 16
#define HEAD_DIMn 64
#define D_STATEn 64
#define CHUNKn 64
#define NCHUNK (SEQ_L / CHUNKn)          // 64
#define BL (B_SZn * SEQ_L)               // 16384
#define XDBL_N (N_HEADSn + 2 * D_STATEn) // 144

typedef __hip_bfloat16 bf16;
typedef __bf16 bf16x8 __attribute__((ext_vector_type(8)));
typedef float f32x4 __attribute__((ext_vector_type(4)));

__device__ __forceinline__ float silu_f(float v) {
    return v / (1.0f + expf(-v));
}
__device__ __forceinline__ float b2f(unsigned short u) {
    return __uint_as_float((unsigned)u << 16);
}
__device__ __forceinline__ unsigned short f2b(float f) {
    bf16 h = __float2bfloat16(f);
    return *(unsigned short*)&h;
}
__device__ __forceinline__ void stf(float* p, float v) { *p = v; }
__device__ __forceinline__ void stf(bf16* p, float v) { *p = __float2bfloat16(v); }

__device__ __forceinline__ float4 us4_to_f4(ushort4 u) {
    float4 f;
    f.x = b2f(u.x); f.y = b2f(u.y); f.z = b2f(u.z); f.w = b2f(u.w);
    return f;
}

// async global->LDS 16B copy (m97/m193-proven pattern).
__device__ __forceinline__ void async_copy16(void* lds, const void* g) {
    __builtin_amdgcn_global_load_lds(
        (const __attribute__((address_space(1))) unsigned int*)g,
        (__attribute__((address_space(3))) unsigned int*)lds, 16, 0, 0);
}

// ---------------------------------------------------------------------------
// x (f32) -> bf16 elementwise convert
// ---------------------------------------------------------------------------
__global__ __launch_bounds__(256) void cvt_f32_bf16(
    const float* __restrict__ in, bf16* __restrict__ out) {
    const int idx = blockIdx.x * 256 + threadIdx.x;
    float4 v = *(const float4*)(in + (size_t)idx * 4);
    ushort4 o;
    o.x = f2b(v.x); o.y = f2b(v.y); o.z = f2b(v.z); o.w = f2b(v.w);
    *(ushort4*)((unsigned short*)out + (size_t)idx * 4) = o;
}

// ---------------------------------------------------------------------------
// Transpose + convert: out[c][r] = bf16(in[r][c]).  in [R][C] f32.
// ---------------------------------------------------------------------------
__global__ __launch_bounds__(256) void transpose_cvt(
    const float* __restrict__ in, bf16* __restrict__ out, int R, int C) {
    __shared__ float t[32][33];
    const int bc = blockIdx.x * 32, br = blockIdx.y * 32;
    const int tx = threadIdx.x & 31, ty = threadIdx.x >> 5;  // ty 0..7
#pragma unroll
    for (int i = ty; i < 32; i += 8) {
        int r = br + i, c = bc + tx;
        t[i][tx] = (r < R && c < C) ? in[(size_t)r * C + c] : 0.f;
    }
    __syncthreads();
#pragma unroll
    for (int i = ty; i < 32; i += 8) {
        int c = bc + i, r = br + tx;
        if (c < C && r < R) out[(size_t)c * R + r] = __float2bfloat16(t[tx][i]);
    }
}

// ---------------------------------------------------------------------------
// bf16 MFMA GEMM: C[M,N] = A[M,K] @ Bt[N,K]^T.  128x128 tile, BK=64, 4 waves,
// global_load_lds staging, XCD-aware block swizzle (T1).
// ---------------------------------------------------------------------------
template <typename TO>
__global__ __launch_bounds__(256) void gemm_mfma(
    const bf16* __restrict__ A, const bf16* __restrict__ Bt,
    TO* __restrict__ C, int M, int N, int K) {
    __shared__ __align__(16) unsigned short Al[2][128 * 32];
    __shared__ __align__(16) unsigned short Bl[2][128 * 32];
    const int tid = threadIdx.x;
    const int wave = tid >> 6, lane = tid & 63;
    const int wm = (wave >> 1) * 64, wn = (wave & 1) * 64;
    int lin = blockIdx.y * gridDim.x + blockIdx.x;
    const int nwg = gridDim.x * gridDim.y;
    if ((nwg & 7) == 0) lin = (lin & 7) * (nwg >> 3) + (lin >> 3);
    const int bm = (lin / gridDim.x) * 128, bn = (lin % gridDim.x) * 128;
    f32x4 acc[4][4];
#pragma unroll
    for (int m = 0; m < 4; ++m)
#pragma unroll
        for (int n = 0; n < 4; ++n) acc[m][n] = (f32x4)(0.f);

    const int lrow = lane & 15, lk8 = (lane >> 4) * 8;
    const int srow = tid >> 2, sc8 = (tid & 3) * 8;
    for (int k0 = 0; k0 < K; k0 += 64) {
#pragma unroll
        for (int h = 0; h < 2; ++h) {
            const int kh = k0 + h * 32;
            async_copy16((char*)&Al[h][0] + (size_t)(wave * 64) * 16,
                         A + (size_t)(bm + srow) * K + kh + sc8);
            async_copy16((char*)&Al[h][0] + (size_t)(256 + wave * 64) * 16,
                         A + (size_t)(bm + 64 + srow) * K + kh + sc8);
            async_copy16((char*)&Bl[h][0] + (size_t)(wave * 64) * 16,
                         Bt + (size_t)(bn + srow) * K + kh + sc8);
            async_copy16((char*)&Bl[h][0] + (size_t)(256 + wave * 64) * 16,
                         Bt + (size_t)(bn + 64 + srow) * K + kh + sc8);
        }
        __syncthreads();
#pragma unroll
        for (int h = 0; h < 2; ++h) {
            bf16x8 af[4], bfr[4];
#pragma unroll
            for (int m = 0; m < 4; ++m)
                af[m] = *(const bf16x8*)(&Al[h][(wm + m * 16 + lrow) * 32 + lk8]);
#pragma unroll
            for (int n = 0; n < 4; ++n)
                bfr[n] = *(const bf16x8*)(&Bl[h][(wn + n * 16 + lrow) * 32 + lk8]);
#pragma unroll
            for (int m = 0; m < 4; ++m)
#pragma unroll
                for (int n = 0; n < 4; ++n)
                    acc[m][n] = __builtin_amdgcn_mfma_f32_16x16x32_bf16(
                        af[m], bfr[n], acc[m][n], 0, 0, 0);
        }
        __syncthreads();
    }
#pragma unroll
    for (int m = 0; m < 4; ++m) {
#pragma unroll
        for (int n = 0; n < 4; ++n) {
#pragma unroll
            for (int r = 0; r < 4; ++r) {
                int row = bm + wm + m * 16 + (lane >> 4) * 4 + r;
                int col = bn + wn + n * 16 + (lane & 15);
                if (row < M && col < N)
                    stf(&C[(size_t)row * N + col], acc[m][n][r]);
            }
        }
    }
}

// ---------------------------------------------------------------------------
// Depthwise conv + bias + silu, register-rolling over an 8-row L-tile.
// Block = (b, l0..l0+7) x all 2048 channels; thread owns 4 x-ch + 4 z-ch.
// 11 row-reads per 8 outputs (vs 32 in per-l layout) — kills the 2x overfetch.
// ---------------------------------------------------------------------------
__global__ __launch_bounds__(256) void conv_silu_kernel(
    const bf16* __restrict__ xz,
    const float* __restrict__ kx, const float* __restrict__ bx,
    const float* __restrict__ kz, const float* __restrict__ bz,
    bf16* __restrict__ xi, bf16* __restrict__ zo) {
    const int tid = threadIdx.x;
    const int d4 = tid * 4;                    // 0..1020
    const int blk = blockIdx.x;                // BL/8 blocks
    const int l0 = (blk * 8) & (SEQ_L - 1);
    const int b = (blk * 8) >> 12;             // /SEQ_L
    const unsigned short* base = (const unsigned short*)xz +
                                 ((size_t)b * SEQ_L) * (2 * D_INNERn);
    float4 wx[4], wz[4];
#pragma unroll
    for (int k = 0; k < 4; ++k) {
        wx[k] = *(const float4*)(kx + k * D_INNERn + d4);
        wz[k] = *(const float4*)(kz + k * D_INNERn + d4);
    }
    const float4 bxv = *(const float4*)(bx + d4);
    const float4 bzv = *(const float4*)(bz + d4);
    // window[k] = row (l-1+k) for current output l
    float4 vx[4], vz[4];
#pragma unroll
    for (int j = 0; j < 3; ++j) {
        int l = l0 - 1 + j;
        if (l >= 0) {
            const unsigned short* row = base + (size_t)l * (2 * D_INNERn);
            vx[j] = us4_to_f4(*(const ushort4*)(row + d4));
            vz[j] = us4_to_f4(*(const ushort4*)(row + D_INNERn + d4));
        } else {
            vx[j] = make_float4(0.f, 0.f, 0.f, 0.f);
            vz[j] = make_float4(0.f, 0.f, 0.f, 0.f);
        }
    }
    unsigned short* xout = (unsigned short*)xi;
    unsigned short* zout = (unsigned short*)zo;
#pragma unroll
    for (int j = 0; j < 8; ++j) {
        const int lread = l0 + 2 + j;
        if (lread < SEQ_L) {
            const unsigned short* row = base + (size_t)lread * (2 * D_INNERn);
            vx[3] = us4_to_f4(*(const ushort4*)(row + d4));
            vz[3] = us4_to_f4(*(const ushort4*)(row + D_INNERn + d4));
        } else {
            vx[3] = make_float4(0.f, 0.f, 0.f, 0.f);
            vz[3] = make_float4(0.f, 0.f, 0.f, 0.f);
        }
        float4 ax = bxv, az = bzv;
#pragma unroll
        for (int k = 0; k < 4; ++k) {
            ax.x += vx[k].x * wx[k].x; ax.y += vx[k].y * wx[k].y;
            ax.z += vx[k].z * wx[k].z; ax.w += vx[k].w * wx[k].w;
            az.x += vz[k].x * wz[k].x; az.y += vz[k].y * wz[k].y;
            az.z += vz[k].z * wz[k].z; az.w += vz[k].w * wz[k].w;
        }
        ushort4 ox, oz;
        ox.x = f2b(silu_f(ax.x)); ox.y = f2b(silu_f(ax.y));
        ox.z = f2b(silu_f(ax.z)); ox.w = f2b(silu_f(ax.w));
        oz.x = f2b(silu_f(az.x)); oz.y = f2b(silu_f(az.y));
        oz.z = f2b(silu_f(az.z)); oz.w = f2b(silu_f(az.w));
        const size_t obase = ((size_t)b * SEQ_L + l0 + j) * D_INNERn + d4;
        *(ushort4*)(xout + obase) = ox;
        *(ushort4*)(zout + obase) = oz;
        // roll window (static indices after unroll)
        vx[0] = vx[1]; vx[1] = vx[2]; vx[2] = vx[3];
        vz[0] = vz[1]; vz[1] = vz[2]; vz[2] = vz[3];
    }
}

// ---------------------------------------------------------------------------
// dt = softplus(x_dbl[..., :16] + dt_bias)   (xdbl bf16)
// ---------------------------------------------------------------------------
__global__ __launch_bounds__(256) void dt_kernel(
    const unsigned short* __restrict__ xdbl, const float* __restrict__ dt_bias,
    float* __restrict__ dtp) {
    const int idx = blockIdx.x * 256 + threadIdx.x;  // BL*16
    const int h = idx & 15;
    const int r = idx >> 4;
    float v = b2f(xdbl[(size_t)r * XDBL_N + h]) + dt_bias[h];
    dtp[idx] = (v > 20.f) ? v : log1pf(expf(v));
}

// ---------------------------------------------------------------------------
// MFMA SSD chunk: per (b,c,h) block, 4 waves.  xdbl bf16; y, S bf16 out.
// ---------------------------------------------------------------------------
__global__ __launch_bounds__(256) void ssd_chunk_mfma(
    const unsigned short* __restrict__ xdbl, const bf16* __restrict__ xi,
    const float* __restrict__ dtp, const float* __restrict__ A_log,
    const float* __restrict__ Dvec,
    unsigned short* __restrict__ y, unsigned short* __restrict__ S,
    float* __restrict__ acum_g, float* __restrict__ rchunk) {
    __shared__ __align__(16) unsigned short sBb[64 * 72];  // B[s][n]
    __shared__ __align__(16) unsigned short sCb[64 * 72];  // C[l][n]
    __shared__ __align__(16) unsigned short sXT[64 * 72];  // X^T[p][s]
    __shared__ __align__(16) unsigned short sGb[64 * 72];  // G[l][s]
    __shared__ __align__(16) unsigned short sWB[64 * 72];  // (w·B)^T[n][s]
    __shared__ float sdtp[64], sacum[64], sw[64];
    const int bid = blockIdx.x;          // ((b*64 + c)*16 + h)
    const int h = bid & 15;
    const int bc = bid >> 4;
    const int c = bc & (NCHUNK - 1);
    const int b = bc >> 6;
    const int tid = threadIdx.x;
    const int wave = tid >> 6, lane = tid & 63;
    const int lrow = lane & 15, lk8 = (lane >> 4) * 8;
    const int row0 = b * SEQ_L + c * CHUNKn;
    const float Ah = -expf(A_log[h]);
    const float Dh = Dvec[h];

    if (tid < 64) sdtp[tid] = dtp[(size_t)(row0 + tid) * N_HEADSn + h];
    const unsigned short* xius = (const unsigned short*)xi;
#pragma unroll
    for (int it = 0; it < 16; ++it) {
        int e = tid + it * 256;
        int s = e >> 6, n = e & 63;
        const unsigned short* xr = xdbl + (size_t)(row0 + s) * XDBL_N + N_HEADSn;
        sBb[s * 72 + n] = xr[n];
        sCb[s * 72 + n] = xr[D_STATEn + n];
        sXT[n * 72 + s] = xius[(size_t)(row0 + s) * D_INNERn + h * HEAD_DIMn + n];
    }
    __syncthreads();
    if (wave == 0) {
        float v = Ah * sdtp[lane];
#pragma unroll
        for (int o = 1; o < 64; o <<= 1) {
            float t = __shfl_up(v, o);
            if (lane >= o) v += t;
        }
        sacum[lane] = v;
        float last = __shfl(v, 63);
        sw[lane] = expf(last - v) * sdtp[lane];
        acum_g[(size_t)bid * 64 + lane] = v;
        if (lane == 63) rchunk[bid] = expf(v);
    }
    // MFMA1: Graw = C·B^T
    f32x4 acc1[4];
#pragma unroll
    for (int t = 0; t < 4; ++t) acc1[t] = (f32x4)(0.f);
#pragma unroll
    for (int ks = 0; ks < 2; ++ks) {
        bf16x8 a = *(const bf16x8*)(&sCb[(wave * 16 + lrow) * 72 + ks * 32 + lk8]);
#pragma unroll
        for (int t = 0; t < 4; ++t) {
            bf16x8 bb = *(const bf16x8*)(&sBb[(t * 16 + lrow) * 72 + ks * 32 + lk8]);
            acc1[t] = __builtin_amdgcn_mfma_f32_16x16x32_bf16(a, bb, acc1[t], 0, 0, 0);
        }
    }
    __syncthreads();
#pragma unroll
    for (int t = 0; t < 4; ++t) {
#pragma unroll
        for (int r = 0; r < 4; ++r) {
            int l = wave * 16 + (lane >> 4) * 4 + r;
            int s = t * 16 + lrow;
            float val = 0.f;
            if (l >= s) val = acc1[t][r] * expf(sacum[l] - sacum[s]) * sdtp[s];
            sGb[l * 72 + s] = f2b(val);
        }
    }
#pragma unroll
    for (int it = 0; it < 16; ++it) {
        int e = tid + it * 256;
        int s = e >> 6, n = e & 63;
        sWB[n * 72 + s] = f2b(sw[s] * b2f(sBb[s * 72 + n]));
    }
    __syncthreads();
    f32x4 acc2[4], acc3[4];
#pragma unroll
    for (int t = 0; t < 4; ++t) { acc2[t] = (f32x4)(0.f); acc3[t] = (f32x4)(0.f); }
#pragma unroll
    for (int ks = 0; ks < 2; ++ks) {
        bf16x8 a2 = *(const bf16x8*)(&sGb[(wave * 16 + lrow) * 72 + ks * 32 + lk8]);
        bf16x8 a3 = *(const bf16x8*)(&sXT[(wave * 16 + lrow) * 72 + ks * 32 + lk8]);
#pragma unroll
        for (int t = 0; t < 4; ++t) {
            bf16x8 b2v = *(const bf16x8*)(&sXT[(t * 16 + lrow) * 72 + ks * 32 + lk8]);
            bf16x8 b3v = *(const bf16x8*)(&sWB[(t * 16 + lrow) * 72 + ks * 32 + lk8]);
            acc2[t] = __builtin_amdgcn_mfma_f32_16x16x32_bf16(a2, b2v, acc2[t], 0, 0, 0);
            acc3[t] = __builtin_amdgcn_mfma_f32_16x16x32_bf16(a3, b3v, acc3[t], 0, 0, 0);
        }
    }
#pragma unroll
    for (int t = 0; t < 4; ++t) {
#pragma unroll
        for (int r = 0; r < 4; ++r) {
            int rr = wave * 16 + (lane >> 4) * 4 + r;
            int cc = t * 16 + lrow;
            float xv = b2f(sXT[cc * 72 + rr]);
            y[(size_t)(row0 + rr) * D_INNERn + h * HEAD_DIMn + cc] =
                f2b(acc2[t][r] + Dh * xv);
            S[(size_t)bid * 4096 + rr * 64 + cc] = f2b(acc3[t][r]);
        }
    }
}

// ---------------------------------------------------------------------------
// Inter-chunk scan (bf16 S, f32 running state): S[c] <- state ENTERING c.
// ---------------------------------------------------------------------------
__global__ __launch_bounds__(256) void chunk_scan_kernel(
    unsigned short* __restrict__ S, const float* __restrict__ rchunk) {
    const int idx = blockIdx.x * 256 + threadIdx.x;  // BH * 2048
    const int pn2 = (idx & 2047) * 2;
    const int bh = idx >> 11;
    const int h = bh & 15;
    const int b = bh >> 4;
    float P0 = 0.f, P1 = 0.f;
    for (int c = 0; c < NCHUNK; ++c) {
        int bid = (b * NCHUNK + c) * N_HEADSn + h;
        size_t off = (size_t)bid * 4096 + pn2;
        unsigned int v = *(unsigned int*)(S + off);
        float s0 = b2f((unsigned short)(v & 0xffff));
        float s1 = b2f((unsigned short)(v >> 16));
        *(unsigned int*)(S + off) =
            (unsigned int)f2b(P0) | ((unsigned int)f2b(P1) << 16);
        float rc = rchunk[bid];
        P0 = rc * P0 + s0;
        P1 = rc * P1 + s1;
    }
}

// ---------------------------------------------------------------------------
// MFMA Y_off: y[l][p] += exp(acum[l]) * sum_n C[l][n] * P[p][n]  (all bf16)
// ---------------------------------------------------------------------------
__global__ __launch_bounds__(256) void yoff_mfma(
    const unsigned short* __restrict__ xdbl, const unsigned short* __restrict__ S,
    const float* __restrict__ acum_g, unsigned short* __restrict__ y) {
    __shared__ __align__(16) unsigned short sCb[64 * 72];
    __shared__ __align__(16) unsigned short sP[64 * 72];
    __shared__ float se[64];
    const int bid = blockIdx.x;
    const int h = bid & 15;
    const int bc = bid >> 4;
    const int c = bc & (NCHUNK - 1);
    const int b = bc >> 6;
    const int tid = threadIdx.x;
    const int wave = tid >> 6, lane = tid & 63;
    const int lrow = lane & 15, lk8 = (lane >> 4) * 8;
    const int row0 = b * SEQ_L + c * CHUNKn;
    if (tid < 64) se[tid] = expf(acum_g[(size_t)bid * 64 + tid]);
#pragma unroll
    for (int it = 0; it < 16; ++it) {
        int e = tid + it * 256;
        int r = e >> 6, n = e & 63;
        sCb[r * 72 + n] = xdbl[(size_t)(row0 + r) * XDBL_N + N_HEADSn + D_STATEn + n];
        sP[r * 72 + n] = S[(size_t)bid * 4096 + e];
    }
    __syncthreads();
    f32x4 acc[4];
#pragma unroll
    for (int t = 0; t < 4; ++t) acc[t] = (f32x4)(0.f);
#pragma unroll
    for (int ks = 0; ks < 2; ++ks) {
        bf16x8 a = *(const bf16x8*)(&sCb[(wave * 16 + lrow) * 72 + ks * 32 + lk8]);
#pragma unroll
        for (int t = 0; t < 4; ++t) {
            bf16x8 bb = *(const bf16x8*)(&sP[(t * 16 + lrow) * 72 + ks * 32 + lk8]);
            acc[t] = __builtin_amdgcn_mfma_f32_16x16x32_bf16(a, bb, acc[t], 0, 0, 0);
        }
    }
#pragma unroll
    for (int t = 0; t < 4; ++t) {
#pragma unroll
        for (int r = 0; r < 4; ++r) {
            int l = wave * 16 + (lane >> 4) * 4 + r;
            int p = t * 16 + lrow;
            size_t idx = (size_t)(row0 + l) * D_INNERn + h * HEAD_DIMn + p;
            y[idx] = f2b(b2f(y[idx]) + acc[t][r] * se[l]);
        }
    }
}

// ---------------------------------------------------------------------------
// y_bf = bf16( RMSNorm(y * silu(z)) * norm_weight )   (y input bf16)
// ---------------------------------------------------------------------------
__global__ __launch_bounds__(256) void gate_norm_kernel(
    const unsigned short* __restrict__ y, const bf16* __restrict__ zb,
    const float* __restrict__ nw, bf16* __restrict__ y_bf) {
    const int row = blockIdx.x;
    const int tid = threadIdx.x;
    const size_t base = (size_t)row * D_INNERn + tid * 4;
    ushort4 yu = *(const ushort4*)(y + base);
    ushort4 zu = *(const ushort4*)((const unsigned short*)zb + base);
    float v0 = b2f(yu.x) * silu_f(b2f(zu.x));
    float v1 = b2f(yu.y) * silu_f(b2f(zu.y));
    float v2 = b2f(yu.z) * silu_f(b2f(zu.z));
    float v3 = b2f(yu.w) * silu_f(b2f(zu.w));
    float ss = v0 * v0 + v1 * v1 + v2 * v2 + v3 * v3;
#pragma unroll
    for (int o = 32; o > 0; o >>= 1) ss += __shfl_xor(ss, o);
    __shared__ float sred[4];
    if ((tid & 63) == 0) sred[tid >> 6] = ss;
    __syncthreads();
    float total = sred[0] + sred[1] + sred[2] + sred[3];
    float scale = rsqrtf(total * (1.0f / D_INNERn) + 1e-5f);
    float4 wv = *(const float4*)(nw + tid * 4);
    ushort4 o4;
    o4.x = f2b(v0 * scale * wv.x);
    o4.y = f2b(v1 * scale * wv.y);
    o4.z = f2b(v2 * scale * wv.z);
    o4.w = f2b(v3 * scale * wv.w);
    *(ushort4*)((unsigned short*)y_bf + base) = o4;
}

// ---------------------------------------------------------------------------
extern "C" void kernel_launch(void* const* d_in, const int* in_sizes, int n_in,
                              void* d_out, int out_size, void* d_ws, size_t ws_size,
                              hipStream_t stream) {
    (void)in_sizes; (void)n_in; (void)out_size; (void)ws_size;
    const float* x       = (const float*)d_in[0];
    const float* W_in    = (const float*)d_in[1];
    const float* ckx     = (const float*)d_in[2];
    const float* cbx     = (const float*)d_in[3];
    const float* ckz     = (const float*)d_in[4];
    const float* cbz     = (const float*)d_in[5];
    const float* W_xdbl  = (const float*)d_in[6];
    const float* dt_bias = (const float*)d_in[7];
    const float* A_log   = (const float*)d_in[8];
    const float* Dvec    = (const float*)d_in[9];
    const float* nw      = (const float*)d_in[10];
    const float* W_out   = (const float*)d_in[11];
    float* out = (float*)d_out;   // f32 output (round-6 verified)
    char* w = (char*)d_ws;

    // Workspace layout (bytes), total 212,877,312 — proven size.
    bf16*  xz     = (bf16*)(w);               // [BL][2048] bf16 = 67,108,864
    unsigned short* y = (unsigned short*)(w); // alias: bf16 [BL][1024] (xz dead)
    bf16*  xi     = (bf16*)(w + 67108864);    // [BL][1024] bf16 = 33,554,432
    bf16*  zb     = (bf16*)(w + 100663296);   // [BL][1024] bf16 = 33,554,432
    char*  Sreg   = w + 134217728;            // 67,108,864 region, multi-use:
    unsigned short* S = (unsigned short*)Sreg;//   [4096][4096] bf16 = 33.5M (SSD)
    bf16*  x_bf   = (bf16*)Sreg;              //   prologue: [BL][512] bf16 = 16.8M
    bf16*  W_in_T = (bf16*)(Sreg + 16777216); //   prologue: [2048][512] bf16 = 2.1M
    bf16*  W_xd_T = (bf16*)(Sreg + 18874368); //   prologue: [144][1024] bf16 = 0.3M
    bf16*  y_bf   = (bf16*)Sreg;              //   epilogue: [BL][1024] bf16 = 33.5M
    bf16*  W_o_T  = (bf16*)(Sreg + 33554432); //   epilogue: [512][1024] bf16 = 1.0M
    unsigned short* xdbl = (unsigned short*)(w + 201326592);  // [BL][144] bf16 = 4.7M
    float* dtp    = (float*)(w + 210763776);  // [BL][16] f32    =  1,048,576
    float* acum   = (float*)(w + 211812352);  // [4096][64] f32  =  1,048,576
    float* rchunk = (float*)(w + 212860928);  // [4096] f32      =     16,384

    // 0. prologue converts (into S region — dead until ssd_chunk)
    cvt_f32_bf16<<<BL * D_MODELn / 1024, 256, 0, stream>>>(x, x_bf);
    transpose_cvt<<<dim3(2048 / 32, 512 / 32), 256, 0, stream>>>(W_in, W_in_T, 512, 2048);
    transpose_cvt<<<dim3(5, 1024 / 32), 256, 0, stream>>>(W_xdbl, W_xd_T, 1024, 144);
    // 1. xz = x @ W_in  (MFMA, BK=64, XCD swizzle), store bf16
    gemm_mfma<bf16><<<dim3(2048 / 128, BL / 128), 256, 0, stream>>>(
        x_bf, W_in_T, xz, BL, 2048, D_MODELn);
    // 2. conv + silu -> xi, zb (register-rolling 8-row tile)
    conv_silu_kernel<<<BL / 8, 256, 0, stream>>>(xz, ckx, cbx, ckz, cbz, xi, zb);
    // 3. x_dbl = xi @ W_xdbl  (MFMA), bf16 out
    gemm_mfma<bf16><<<dim3(2, BL / 128), 256, 0, stream>>>(
        xi, W_xd_T, (bf16*)xdbl, BL, XDBL_N, D_INNERn);
    // 4. dt = softplus(...)
    dt_kernel<<<BL * N_HEADSn / 256, 256, 0, stream>>>(xdbl, dt_bias, dtp);
    // 5. SSD per-chunk (MFMA): Y_diag + states (y, S bf16)
    ssd_chunk_mfma<<<B_SZn * NCHUNK * N_HEADSn, 256, 0, stream>>>(
        xdbl, xi, dtp, A_log, Dvec, y, S, acum, rchunk);
    // 6. inter-chunk scan (in place, bf16)
    chunk_scan_kernel<<<B_SZn * N_HEADSn * 2048 / 256, 256, 0, stream>>>(S, rchunk);
    // 7. Y_off accumulate (MFMA, bf16 RMW)
    yoff_mfma<<<B_SZn * NCHUNK * N_HEADSn, 256, 0, stream>>>(xdbl, S, acum, y);
    // 8. epilogue: W_out^T (S dead after yoff), gate+norm -> y_bf
    transpose_cvt<<<dim3(512 / 32, 1024 / 32), 256, 0, stream>>>(W_out, W_o_T, 1024, 512);
    gate_norm_kernel<<<BL, 256, 0, stream>>>(y, zb, nw, y_bf);
    // 9. out = y @ W_out  (MFMA), store f32 to d_out
    gemm_mfma<float><<<dim3(512 / 128, BL / 128), 256, 0, stream>>>(
        y_bf, W_o_T, out, BL, D_MODELn, D_INNERn);
}